// Round 9
// baseline (379.025 us; speedup 1.0000x reference)
//
#include <hip/hip_runtime.h>
#include <cstdint>

// NeuralMemory forward. MFMA bf16 for big GEMMs + per-chunk MLP grad/retrieve.
// Shapes (fixed): B=4 T=8192 DIM=512 H=8 D=64 C=64 N=128 BH=32
// R5: split k_norm_scale -> k_scale + MFMA k_lr_gate (559->468us).
// R6/R7: sbf=bf16(seq*scale) staged once; XCD-chunk swizzle (468->405us).
// R8: k_grad conflict/VALU cleanup (405->380us).
// R9/R10: B-direct-from-L2 REGRESSED (latency entered MFMA critical path).
// R11: revert gemm to R8; k_scan 4-lane+prefetch (380->378us).
// R12: gemm staging via __builtin_amdgcn_global_load_lds width=16 (m97
//     ladder lever: kills the VGPR round-trip + staging VALU). LDS dest is
//     linear [128][64] (gload_lds writes base+lane*16); XOR swizzle
//     group^=(row&7) applied on the GLOBAL source address + on reads
//     (m173 pattern). MODE1 A keeps padded register-convert path.
// R13: identical resubmit (R12 bench was an infra failure, no GPU verdict).
#define EPS     1.1920929e-07f
#define MAX_LR  0.01f
#define BB      4
#define TT      8192
#define DIMM    512
#define HH      8
#define DD      64
#define CC      64
#define NN      128
#define BHH     32
#define LDSP    72      // LDS row stride (bf16) for padded layouts

typedef __attribute__((ext_vector_type(8))) short short8;
typedef __attribute__((ext_vector_type(4))) float f32x4;

__device__ __forceinline__ float sigmoidf_(float x){ return 1.0f/(1.0f+__expf(-x)); }
__device__ __forceinline__ float bf2f(uint32_t lo16){ return __uint_as_float(lo16<<16); }
__device__ __forceinline__ uint16_t f2bf(float f){
    uint32_t x = __float_as_uint(f);
    return (uint16_t)((x + 0x7fffu + ((x>>16)&1u)) >> 16);   // RNE
}
__device__ __forceinline__ uint32_t pk2(float a, float b){
    return (uint32_t)f2bf(a) | ((uint32_t)f2bf(b)<<16);
}
// async global->LDS, 16B/lane. LDS dest = wave-uniform base + lane*16.
__device__ __forceinline__ void gload_lds16(const uint16_t* g, uint16_t* l){
    __builtin_amdgcn_global_load_lds(
        (const __attribute__((address_space(1))) unsigned int*)g,
        (__attribute__((address_space(3))) unsigned int*)l, 16, 0, 0);
}

// 64x64x64 GEMM slice on padded-72 LDS (used by k_grad/k_retrieve/k_lr_gate).
__device__ __forceinline__ void gemm64(const uint16_t* A, const uint16_t* B,
                                       int strip, int q, int col, f32x4* acc)
{
    #pragma unroll
    for (int ks=0; ks<64; ks+=32){
        short8 af = *(const short8*)&A[(strip*16+col)*LDSP + ks + q*8];
        #pragma unroll
        for (int nt=0;nt<4;nt++){
            short8 bf = *(const short8*)&B[(nt*16+col)*LDSP + ks + q*8];
            acc[nt] = __builtin_amdgcn_mfma_f32_16x16x32_bf16(af, bf, acc[nt], 0,0,0);
        }
    }
}

// ---------------------------------------------------------------------------
// K1a: wave-per-row rmsnorm scale + bf16(seq*scale) stream-out.
// ---------------------------------------------------------------------------
__global__ __launch_bounds__(256) void k_scale(
    const float* __restrict__ seq, float* __restrict__ scale,
    uint16_t* __restrict__ sbf)
{
    int wave = threadIdx.x >> 6, lane = threadIdx.x & 63;
    int row = blockIdx.x*4 + wave;          // b*T + t
    const float4* sp = (const float4*)&seq[(size_t)row*DIMM + lane*8];
    float4 x0 = sp[0], x1 = sp[1];
    float ss = x0.x*x0.x + x0.y*x0.y + x0.z*x0.z + x0.w*x0.w
             + x1.x*x1.x + x1.y*x1.y + x1.z*x1.z + x1.w*x1.w;
    #pragma unroll
    for (int o=32;o;o>>=1) ss += __shfl_xor(ss,o,64);
    float sc = rsqrtf(ss*(1.0f/DIMM)+EPS);
    if (lane==0) scale[row] = sc;
    uint4 v;
    v.x = pk2(x0.x*sc, x0.y*sc);
    v.y = pk2(x0.z*sc, x0.w*sc);
    v.z = pk2(x1.x*sc, x1.y*sc);
    v.w = pk2(x1.z*sc, x1.w*sc);
    *(uint4*)&sbf[(size_t)row*DIMM + lane*8] = v;
}

// ---------------------------------------------------------------------------
// K1b-prep: pack [Wstep|Wgate] -> bf16 B^T rows [16][512] (row = out col).
// ---------------------------------------------------------------------------
__global__ __launch_bounds__(256) void k_pack_wsg(
    const float* __restrict__ Wstep, const float* __restrict__ Wgate,
    uint16_t* __restrict__ wsg)
{
    int g = blockIdx.x*256 + threadIdx.x;   // 8192 total
    int j = g >> 9, k = g & 511;
    float v = (j < HH) ? Wstep[k*HH + j] : Wgate[k*HH + (j-HH)];
    wsg[j*DIMM + k] = f2bf(v);
}

// ---------------------------------------------------------------------------
// K1c: precompute w1^T/w2^T (bf16 + f32) and w2 bf16 row-major. One block.
// ---------------------------------------------------------------------------
__global__ __launch_bounds__(256) void k_pack_w(
    const float* __restrict__ w1, const float* __restrict__ w2,
    uint16_t* __restrict__ w1t_bf, uint16_t* __restrict__ w2t_bf,
    uint16_t* __restrict__ w2b_bf, float* __restrict__ w1t_f,
    float* __restrict__ w2t_f)
{
    __shared__ float t1[64][65];
    __shared__ float t2[64][65];
    int tx = threadIdx.x & 63, ty = threadIdx.x >> 6;   // 64 x 4
    #pragma unroll
    for (int i=0;i<16;i++){
        int row = ty*16 + i;
        float v1 = w1[row*DD + tx];
        float v2 = w2[row*DD + tx];
        t1[row][tx] = v1;
        t2[row][tx] = v2;
        w2b_bf[row*DD + tx] = f2bf(v2);
    }
    __syncthreads();
    #pragma unroll
    for (int i=0;i<16;i++){
        int row = ty*16 + i;
        float v1 = t1[tx][row];     // w1[p=tx][d1=row] -> w1t[row][tx]
        float v2 = t2[tx][row];
        w1t_f[row*DD + tx] = v1;
        w1t_bf[row*DD + tx] = f2bf(v1);
        w2t_f[row*DD + tx] = v2;
        w2t_bf[row*DD + tx] = f2bf(v2);
    }
}

// ---------------------------------------------------------------------------
// K1b: lr/gate thin GEMM via MFMA: (32768 x 512) @ (512 x 16).
// ---------------------------------------------------------------------------
__global__ __launch_bounds__(256) void k_lr_gate(
    const uint16_t* __restrict__ sbf, const uint16_t* __restrict__ wsg,
    float* __restrict__ lr_t, float* __restrict__ gate_t)
{
    __shared__ uint16_t Asl[128][LDSP];
    int tid = threadIdx.x;
    int w = tid>>6, lane = tid&63, q = lane>>4, col = lane&15;
    int m0 = blockIdx.x*128;

    f32x4 acc[2];
    acc[0] = (f32x4){0.f,0.f,0.f,0.f};
    acc[1] = (f32x4){0.f,0.f,0.f,0.f};

    for (int k0=0;k0<DIMM;k0+=64){
        #pragma unroll
        for (int s=0;s<4;s++){
            int seg = s*256 + tid;
            int row = seg>>3, kk = seg&7;
            uint4 v = *(const uint4*)&sbf[(size_t)(m0+row)*DIMM + k0 + kk*8];
            *(uint4*)&Asl[row][kk*8] = v;
        }
        __syncthreads();
        #pragma unroll
        for (int ks=0;ks<64;ks+=32){
            short8 bf = *(const short8*)&wsg[(size_t)col*DIMM + k0 + ks + q*8];
            #pragma unroll
            for (int mt=0;mt<2;mt++){
                short8 af = *(const short8*)&Asl[w*32 + mt*16 + col][ks + q*8];
                acc[mt] = __builtin_amdgcn_mfma_f32_16x16x32_bf16(af, bf, acc[mt], 0,0,0);
            }
        }
        __syncthreads();
    }

    #pragma unroll
    for (int mt=0;mt<2;mt++){
        #pragma unroll
        for (int reg=0;reg<4;reg++){
            int m = m0 + w*32 + mt*16 + q*4 + reg;
            int b = m>>13, t = m&8191;
            float val = sigmoidf_(acc[mt][reg]);
            if (col < HH){
                lr_t[(size_t)m*HH + col] = val*MAX_LR;
            } else {
                int j = t-63;
                if (j >= 0)
                    gate_t[((size_t)b*TT + j)*HH + (col-HH)] = val;
            }
        }
    }
}

// ---------------------------------------------------------------------------
// K2: chunk means (unchanged — f32 path kept for gate precision)
// ---------------------------------------------------------------------------
__global__ __launch_bounds__(512) void k_chunk_gates(
    const float* __restrict__ seq, const float* __restrict__ scale,
    const float* __restrict__ Wmom, const float* __restrict__ Wdecay,
    float* __restrict__ mom, float* __restrict__ dec)
{
    int blk = blockIdx.x;              // b*N + n
    int b = blk>>7, n = blk&127;
    int tid = threadIdx.x;
    __shared__ float scl[CC];
    if (tid < CC) scl[tid] = scale[b*TT + n*CC + tid];
    __syncthreads();
    size_t base = ((size_t)b*TT + n*CC)*DIMM + tid;
    float acc=0.f;
    #pragma unroll 8
    for (int j=0;j<CC;j++) acc += seq[base + (size_t)j*DIMM]*scl[j];
    __shared__ float sm[DIMM];
    sm[tid] = acc*(1.0f/CC);
    __syncthreads();
    int wid = tid>>6, lane = tid&63;
    float d1=0.f, d2=0.f;
    #pragma unroll
    for (int i=0;i<8;i++){
        int idx=i*64+lane; float sv=sm[idx];
        d1 += sv*Wmom[idx*HH+wid];
        d2 += sv*Wdecay[idx*HH+wid];
    }
    #pragma unroll
    for (int o=32;o;o>>=1){ d1+=__shfl_down(d1,o,64); d2+=__shfl_down(d2,o,64); }
    if (lane==0){
        mom[(b*HH+wid)*NN + n] = sigmoidf_(d1);
        dec[(b*HH+wid)*NN + n] = sigmoidf_(d2);
    }
}

// ---------------------------------------------------------------------------
// K3a: transpose+convert B matrix (unchanged)
// ---------------------------------------------------------------------------
__global__ __launch_bounds__(256) void k_transpose(
    const float* __restrict__ in, uint16_t* __restrict__ out, int Ncols)
{
    __shared__ float tile[32][33];
    int bx = blockIdx.x*32;   // n
    int by = blockIdx.y*32;   // k
    int lx = threadIdx.x&31, ly = threadIdx.x>>5;   // 32 x 8
    #pragma unroll
    for (int r=0;r<4;r++)
        tile[ly+8*r][lx] = in[(size_t)(by+ly+8*r)*Ncols + bx+lx];
    __syncthreads();
    #pragma unroll
    for (int r=0;r<4;r++)
        out[(size_t)(bx+ly+8*r)*DIMM + by+lx] = f2bf(tile[lx][ly+8*r]);
}

// ---------------------------------------------------------------------------
// K3: MFMA GEMM. MODE 0/2: A+B staged via global_load_lds into linear
// [128][64] LDS with XOR swizzle (group ^= row&7) applied on the global
// source + reads. MODE 1: A f32*scale register-converted into padded
// [128][72]; B uses gload_lds path. XCD-chunk swizzle as before.
// ---------------------------------------------------------------------------
template<int MODE>
__global__ __launch_bounds__(256) void k_gemm_mfma(
    const void* __restrict__ Av, const uint16_t* __restrict__ Bt,
    const float* __restrict__ scale, void* __restrict__ out0,
    void* __restrict__ out1)
{
    __shared__ uint16_t Asl[128*72];   // MODE1: padded 72; MODE0/2: linear 64
    __shared__ uint16_t Bsl[128*64];   // linear 64, swizzled
    __shared__ float sscale[128];
    int tid = threadIdx.x;
    int wave = tid>>6, lane = tid&63;
    int q = lane>>4, col = lane&15;
    // bijective XCD swizzle: hw dispatch is x-fastest, XCD = bid%8.
    int bid = blockIdx.y*gridDim.x + blockIdx.x;
    int xcd = bid & 7, local = bid >> 3;
    int mper = gridDim.y >> 3;                  // m-tiles per XCD
    int m0 = (xcd*mper + local/gridDim.x)*128;
    int n0 = (local%gridDim.x)*128;
    int m_off = (wave&1)*64, n_off = (wave>>1)*64;

    if (MODE==1){
        if (tid<128) sscale[tid] = scale[m0+tid];
        __syncthreads();
    }

    f32x4 acc[4][4];
    #pragma unroll
    for (int i=0;i<4;i++)
        #pragma unroll
        for (int j=0;j<4;j++) acc[i][j] = (f32x4){0.f,0.f,0.f,0.f};

    int srow = wave*32 + (lane>>3);   // staging row (per lane), + s*8
    int sgs  = lane&7;                // staging group slot

    for (int k0=0;k0<DIMM;k0+=64){
        if (MODE!=1){
            const uint16_t* A = (const uint16_t*)Av;
            #pragma unroll
            for (int s=0;s<4;s++){
                int r = srow + s*8;
                gload_lds16(&A[(size_t)(m0+r)*DIMM + k0 + ((sgs ^ (r&7))<<3)],
                            &Asl[(wave*32 + s*8)*64]);
            }
        } else {
            const float* A = (const float*)Av;
            #pragma unroll
            for (int s=0;s<4;s++){
                int seg = s*256 + tid;
                int row = seg>>3, kk = seg&7;
                float sc = sscale[row];
                const float4* ap = (const float4*)&A[(size_t)(m0+row)*DIMM + k0 + kk*8];
                float4 a0 = ap[0], a1 = ap[1];
                uint4 v;
                v.x = pk2(a0.x*sc, a0.y*sc);
                v.y = pk2(a0.z*sc, a0.w*sc);
                v.z = pk2(a1.x*sc, a1.y*sc);
                v.w = pk2(a1.z*sc, a1.w*sc);
                *(uint4*)&Asl[row*72 + kk*8] = v;
            }
        }
        #pragma unroll
        for (int s=0;s<4;s++){
            int r = srow + s*8;
            gload_lds16(&Bt[(size_t)(n0+r)*DIMM + k0 + ((sgs ^ (r&7))<<3)],
                        &Bsl[(wave*32 + s*8)*64]);
        }
        __syncthreads();
        #pragma unroll
        for (int ks=0;ks<64;ks+=32){
            short8 af[4], bf[4];
            int g = q + (ks>>3);
            #pragma unroll
            for (int mt=0;mt<4;mt++){
                int r = m_off + mt*16 + col;
                if (MODE==1)
                    af[mt] = *(const short8*)&Asl[r*72 + ks + q*8];
                else
                    af[mt] = *(const short8*)&Asl[r*64 + ((g ^ (r&7))<<3)];
            }
            #pragma unroll
            for (int nt=0;nt<4;nt++){
                int rb = n_off + nt*16 + col;
                bf[nt] = *(const short8*)&Bsl[rb*64 + ((g ^ (rb&7))<<3)];
            }
            #pragma unroll
            for (int mt=0;mt<4;mt++)
                #pragma unroll
                for (int nt=0;nt<4;nt++)
                    acc[mt][nt] = __builtin_amdgcn_mfma_f32_16x16x32_bf16(
                        af[mt], bf[nt], acc[mt][nt], 0, 0, 0);
        }
        __syncthreads();
    }

    #pragma unroll
    for (int mt=0;mt<4;mt++){
        #pragma unroll
        for (int reg=0;reg<4;reg++){
            int m = m0 + m_off + mt*16 + q*4 + reg;
            int b = m>>13, t = m&8191;
            if (MODE==0){
                #pragma unroll
                for (int nt=0;nt<4;nt++){
                    int e = n0 + n_off + nt*16 + col;
                    uint16_t* basep = (uint16_t*)((e<512) ? out0 : out1);
                    int ee = e & 511;
                    int h = ee>>6, dk = ee&63;
                    basep[((size_t)(b*HH+h)*TT + t)*DD + dk] = f2bf(acc[mt][nt][reg]);
                }
            } else if (MODE==1){
                int j = t-63;
                if (j>=0){
                    #pragma unroll
                    for (int nt=0;nt<4;nt++){
                        int e = n0 + n_off + nt*16 + col;
                        int h = e>>6, dk = e&63;
                        ((uint16_t*)out0)[((size_t)(b*HH+h)*TT + j)*DD + dk] = f2bf(acc[mt][nt][reg]);
                    }
                }
            } else {
                int tp = t + 63;
                if (tp < TT){
                    #pragma unroll
                    for (int nt=0;nt<4;nt++){
                        int e = n0 + n_off + nt*16 + col;
                        ((float*)out0)[((size_t)b*TT + tp)*DIMM + e] = acc[mt][nt][reg];
                    }
                }
            }
        }
    }
}

// ---------------------------------------------------------------------------
// K4: per-chunk MLP gradient via MFMA. One block per (bh,n), 4 waves.
// Swapped-operand scheme (R8). Outputs -g1^T, -g2^T bf16.
// ---------------------------------------------------------------------------
__global__ __launch_bounds__(256) void k_grad(
    const uint16_t* __restrict__ kbuf, const uint16_t* __restrict__ vbuf,
    const float* __restrict__ lr_t, const uint16_t* __restrict__ w1t_bf,
    const uint16_t* __restrict__ w2t_bf, const uint16_t* __restrict__ w2b_bf,
    uint16_t* __restrict__ g1T, uint16_t* __restrict__ g2T)
{
    __shared__ uint16_t lds[8*64*LDSP];
    __shared__ float lr_sh[64];
    uint16_t* kcB  = lds + 0*64*LDSP;
    uint16_t* kcT  = lds + 1*64*LDSP;
    uint16_t* w1T  = lds + 2*64*LDSP;   // -> dxB
    uint16_t* w2T  = lds + 3*64*LDSP;   // -> dx1T
    uint16_t* w2b  = lds + 4*64*LDSP;
    uint16_t* hA   = lds + 5*64*LDSP;
    uint16_t* hB   = lds + 6*64*LDSP;   // -> dxA
    uint16_t* vB   = lds + 7*64*LDSP;
    uint16_t* dxB  = w1T;
    uint16_t* dx1T = w2T;
    uint16_t* dxA  = hB;

    int bhn = blockIdx.x;
    int bh = bhn>>7, n = bhn&127;
    int b = bh>>3, h = bh&7;
    int tid = threadIdx.x, tx = tid&15, ty = tid>>4;
    int w = tid>>6, lane = tid&63, q = lane>>4, col = lane&15;
    size_t cbase = ((size_t)bh*TT + n*CC)*DD;

    // ---- stage kc (both layouts) + v ----
    #pragma unroll
    for (int r=0;r<4;r++){
        int row = ty*4+r;
        ushort4 k4 = *(const ushort4*)&kbuf[cbase + row*DD + tx*4];
        *(ushort4*)&kcB[row*LDSP + tx*4] = k4;
        kcT[(tx*4+0)*LDSP + row] = k4.x;
        kcT[(tx*4+1)*LDSP + row] = k4.y;
        kcT[(tx*4+2)*LDSP + row] = k4.z;
        kcT[(tx*4+3)*LDSP + row] = k4.w;
        ushort4 v4 = *(const ushort4*)&vbuf[cbase + row*DD + tx*4];
        *(ushort4*)&vB[row*LDSP + tx*4] = v4;
    }
    // ---- stage w1T/w2T/w2b via clean vector copies (precomputed bf16) ----
    {
        int row = tid>>2, sg8 = (tid&3)*16;
        *(uint4*)&w1T[row*LDSP + sg8]     = *(const uint4*)&w1t_bf[row*DD + sg8];
        *(uint4*)&w1T[row*LDSP + sg8 + 8] = *(const uint4*)&w1t_bf[row*DD + sg8 + 8];
        *(uint4*)&w2T[row*LDSP + sg8]     = *(const uint4*)&w2t_bf[row*DD + sg8];
        *(uint4*)&w2T[row*LDSP + sg8 + 8] = *(const uint4*)&w2t_bf[row*DD + sg8 + 8];
        *(uint4*)&w2b[row*LDSP + sg8]     = *(const uint4*)&w2b_bf[row*DD + sg8];
        *(uint4*)&w2b[row*LDSP + sg8 + 8] = *(const uint4*)&w2b_bf[row*DD + sg8 + 8];
    }
    if (tid < 64) lr_sh[tid] = lr_t[((size_t)b*TT + n*CC + tid)*HH + h];
    __syncthreads();

    // ---- G1 (swapped): x1^T = (kc @ w1)^T. Frags: rows d1, cols token ----
    f32x4 a1[4];
    #pragma unroll
    for (int i=0;i<4;i++) a1[i]=(f32x4){0.f,0.f,0.f,0.f};
    gemm64(w1T, kcB, w, q, col, a1);
    float sg[16], hr[16];
    #pragma unroll
    for (int nt=0;nt<4;nt++)
        #pragma unroll
        for (int reg=0;reg<4;reg++){
            int idx = nt*4+reg;
            float x = a1[nt][reg];
            float sgm = sigmoidf_(x);
            sg[idx]=sgm; hr[idx]=x*sgm;
            int d1 = w*16 + q*4 + reg;
            int token = nt*16 + col;
            uint16_t hv = f2bf(x*sgm);
            hA[d1*LDSP + token] = hv;      // natural
            hB[token*LDSP + d1] = hv;      // scatter
        }
    __syncthreads();

    // ---- G2 (swapped): x2^T = (h @ w2)^T ; dx2 = (2/D)*lr*(x2 - v) ----
    f32x4 a2[4];
    #pragma unroll
    for (int i=0;i<4;i++) a2[i]=(f32x4){0.f,0.f,0.f,0.f};
    gemm64(w2T, hB, w, q, col, a2);
    __syncthreads();   // hB/w1T reads done before overwrite with dxA/dxB
    #pragma unroll
    for (int nt=0;nt<4;nt++)
        #pragma unroll
        for (int reg=0;reg<4;reg++){
            int d2 = w*16 + q*4 + reg;
            int token = nt*16 + col;
            float vv = bf2f(vB[token*LDSP + d2]);
            float dx = (2.0f/DD)*lr_sh[token]*(a2[nt][reg]-vv);
            uint16_t dv = f2bf(dx);
            dxA[d2*LDSP + token] = dv;     // natural
            dxB[token*LDSP + d2] = dv;     // scatter
        }
    __syncthreads();

    // ---- G3: g2^T = dx2^T @ h  (rows=d2 strip, cols=d1) ----
    f32x4 a3[4];
    #pragma unroll
    for (int i=0;i<4;i++) a3[i]=(f32x4){0.f,0.f,0.f,0.f};
    gemm64(dxA, hA, w, q, col, a3);
    // ---- G4 (swapped): dh^T = w2 @ dx2^T ; dx1^T = dh^T*silu'(x1^T) ----
    f32x4 a4[4];
    #pragma unroll
    for (int i=0;i<4;i++) a4[i]=(f32x4){0.f,0.f,0.f,0.f};
    gemm64(w2b, dxB, w, q, col, a4);

    size_t gb = (size_t)bhn*4096;
    #pragma unroll
    for (int nt=0;nt<4;nt++)
        #pragma unroll
        for (int reg=0;reg<4;reg++){
            int d2 = w*16 + q*4 + reg;
            int d1 = nt*16 + col;
            g2T[gb + d2*DD + d1] = f2bf(-a3[nt][reg]);
        }
    #pragma unroll
    for (int nt=0;nt<4;nt++)
        #pragma unroll
        for (int reg=0;reg<4;reg++){
            int idx = nt*4+reg;
            int d1 = w*16 + q*4 + reg;
            int token = nt*16 + col;
            float dsl = sg[idx] + hr[idx]*(1.f-sg[idx]);
            dx1T[d1*LDSP + token] = f2bf(a4[nt][reg]*dsl);   // natural
        }
    __syncthreads();

    // ---- G5: g1^T = dx1^T @ kc  (rows=d1 strip, cols=p) ----
    f32x4 a5[4];
    #pragma unroll
    for (int i=0;i<4;i++) a5[i]=(f32x4){0.f,0.f,0.f,0.f};
    gemm64(dx1T, kcT, w, q, col, a5);
    #pragma unroll
    for (int nt=0;nt<4;nt++)
        #pragma unroll
        for (int reg=0;reg<4;reg++){
            int d1 = w*16 + q*4 + reg;
            int p  = nt*16 + col;
            g1T[gb + d1*DD + p] = f2bf(-a5[nt][reg]);
        }
}

// ---------------------------------------------------------------------------
// K5: scans. 8B/thread (4 recurrence lanes) + 4-deep load prefetch.
// ---------------------------------------------------------------------------
__global__ __launch_bounds__(256) void k_scan(
    uint16_t* __restrict__ g1, uint16_t* __restrict__ g2,
    const float* __restrict__ mom, const float* __restrict__ dec)
{
    int blk = blockIdx.x;            // [0,256)
    int arr = blk>>7; int rem = blk&127;
    int bh = rem>>2; int eg = rem&3;
    int e4 = eg*1024 + threadIdx.x*4;
    uint16_t* gp = arr ? g2 : g1;
    __shared__ float smg[NN], sdc[NN];
    if (threadIdx.x < NN){
        smg[threadIdx.x] = mom[bh*NN+threadIdx.x];
        sdc[threadIdx.x] = 1.f - dec[bh*NN+threadIdx.x];
    }
    __syncthreads();
    size_t base = (size_t)bh*NN*4096 + e4;
    float m0=0.f,m1=0.f,m2=0.f,m3=0.f, u0=0.f,u1=0.f,u2=0.f,u3=0.f;
    uint2 p0 = *(const uint2*)&gp[base];
    uint2 p1 = *(const uint2*)&gp[base + 4096];
    uint2 p2 = *(const uint2*)&gp[base + 2*4096];
    uint2 p3 = *(const uint2*)&gp[base + 3*4096];
    for (int t=0; t<NN; t+=4){
        uint2 c0=p0, c1=p1, c2=p2, c3=p3;
        if (t+4 < NN){                       // uniform branch
            p0 = *(const uint2*)&gp[base + (size_t)(t+4)*4096];
            p1 = *(const uint2*)&gp[base + (size_t)(t+5)*4096];
            p2 = *(const uint2*)&gp[base + (size_t)(t+6)*4096];
            p3 = *(const uint2*)&gp[base + (size_t)(t+7)*4096];
        }
        #pragma unroll
        for (int j=0;j<4;j++){
            uint2 c = (j==0)?c0:(j==1)?c1:(j==2)?c2:c3;
            float g = smg[t+j], d = sdc[t+j];
            float v0 = bf2f(c.x&0xffffu), v1 = bf2f(c.x>>16);
            float v2 = bf2f(c.y&0xffffu), v3 = bf2f(c.y>>16);
            m0 = fmaf(g,m0,v0); u0 = fmaf(d,u0,m0);
            m1 = fmaf(g,m1,v1); u1 = fmaf(d,u1,m1);
            m2 = fmaf(g,m2,v2); u2 = fmaf(d,u2,m2);
            m3 = fmaf(g,m3,v3); u3 = fmaf(d,u3,m3);
            uint2 r; r.x = pk2(u0,u1); r.y = pk2(u2,u3);
            *(uint2*)&gp[base + (size_t)(t+j)*4096] = r;
        }
    }
}

// ---------------------------------------------------------------------------
// K6: retrieve via MFMA. One block per (bh,n), 4 waves.
// ---------------------------------------------------------------------------
__global__ __launch_bounds__(256) void k_retrieve(
    const uint16_t* __restrict__ qbuf, const uint16_t* __restrict__ u1T,
    const uint16_t* __restrict__ u2T, const float* __restrict__ w1Tf,
    const float* __restrict__ w2Tf, const float* __restrict__ gamma,
    const float* __restrict__ gate_t, uint16_t* __restrict__ y)
{
    __shared__ uint16_t qc[64*LDSP];
    __shared__ uint16_t W1s[64*LDSP];   // (w1+u1)^T rows: [d1][p]
    __shared__ uint16_t W2s[64*LDSP];   // (w2+u2)^T rows: [d2][d1]
    __shared__ uint16_t hB[64*LDSP];    // h rows: [token][d1]
    __shared__ float gate_sh[64], gam_sh[64];
    int bhn = blockIdx.x;
    int bh = bhn>>7, n = bhn&127;
    int b = bh>>3, h = bh&7;
    int tid = threadIdx.x, tx = tid&15, ty = tid>>4;
    int w = tid>>6, lane = tid&63, q = lane>>4, col = lane&15;
    size_t cbase = ((size_t)bh*TT + n*CC)*DD;
    size_t ub = (size_t)bhn*4096;

    #pragma unroll
    for (int r=0;r<4;r++){
        int row = ty*4+r;     // d_out index for W staging; token for qc
        *(ushort4*)&qc[row*LDSP + tx*4] =
            *(const ushort4*)&qbuf[cbase + row*DD + tx*4];
        ushort4 u14 = *(const ushort4*)&u1T[ub + row*DD + tx*4];
        float4 w1v = *(const float4*)&w1Tf[row*DD + tx*4];
        ushort4 s1;
        s1.x = f2bf(w1v.x + bf2f(u14.x));
        s1.y = f2bf(w1v.y + bf2f(u14.y));
        s1.z = f2bf(w1v.z + bf2f(u14.z));
        s1.w = f2bf(w1v.w + bf2f(u14.w));
        *(ushort4*)&W1s[row*LDSP + tx*4] = s1;
        ushort4 u24 = *(const ushort4*)&u2T[ub + row*DD + tx*4];
        float4 w2v = *(const float4*)&w2Tf[row*DD + tx*4];
        ushort4 s2;
        s2.x = f2bf(w2v.x + bf2f(u24.x));
        s2.y = f2bf(w2v.y + bf2f(u24.y));
        s2.z = f2bf(w2v.z + bf2f(u24.z));
        s2.w = f2bf(w2v.w + bf2f(u24.w));
        *(ushort4*)&W2s[row*LDSP + tx*4] = s2;
    }
    if (tid < 64){
        gate_sh[tid] = gate_t[((size_t)b*TT + n*CC + tid)*HH + h];
        gam_sh[tid]  = gamma[h*DD + tid];
    }
    __syncthreads();

    // G1: x1 = qc @ (w1+u1); h = silu
    f32x4 a1[4];
    #pragma unroll
    for (int i=0;i<4;i++) a1[i]=(f32x4){0.f,0.f,0.f,0.f};
    gemm64(qc, W1s, w, q, col, a1);
    #pragma unroll
    for (int nt=0;nt<4;nt++)
        #pragma unroll
        for (int reg=0;reg<4;reg++){
            float x = a1[nt][reg];
            int token = w*16 + q*4 + reg;
            int d1 = nt*16 + col;
            hB[token*LDSP + d1] = f2bf(x*sigmoidf_(x));
        }
    __syncthreads();

    // G2: x = h @ (w2+u2); rmsnorm(d=64) * (1+gamma) * gate -> y
    f32x4 a2[4];
    #pragma unroll
    for (int i=0;i<4;i++) a2[i]=(f32x4){0.f,0.f,0.f,0.f};
    gemm64(hB, W2s, w, q, col, a2);
    #pragma unroll
    for (int reg=0;reg<4;reg++){
        float p = 0.f;
        #pragma unroll
        for (int nt=0;nt<4;nt++) p += a2[nt][reg]*a2[nt][reg];
        p += __shfl_xor(p,1,64);
        p += __shfl_xor(p,2,64);
        p += __shfl_xor(p,4,64);
        p += __shfl_xor(p,8,64);
        float sclv = rsqrtf(p*(1.0f/DD)+EPS);
        int token = w*16 + q*4 + reg;
        float gt = gate_sh[token];
        size_t yb = ((size_t)b*TT + n*CC + token)*DIMM + h*DD;
        #pragma unroll
        for (int nt=0;nt<4;nt++){
            int d2 = nt*16 + col;
            y[yb + d2] = f2bf(a2[nt][reg]*sclv*(1.f+gam_sh[d2])*gt);
        }
    }
}

// ---------------------------------------------------------------------------
// K7: zero pads (unchanged)
// ---------------------------------------------------------------------------
__global__ __launch_bounds__(256) void k_zero(
    uint16_t* __restrict__ qbuf, float* __restrict__ out, float* __restrict__ gate_t)
{
    int g = blockIdx.x*256 + threadIdx.x;
    const int QN = BHH*63*DD;          // 129024
    const int ON = BB*63*DIMM;         // 129024
    const int GN = BB*63*HH;           // 2016
    if (g < QN){
        int bh = g/4032; int r = g - bh*4032;
        int j = 8129 + (r>>6); int dk = r&63;
        qbuf[((size_t)bh*TT + j)*DD + dk] = 0;
    } else if (g < QN+ON){
        int g2i = g - QN;
        int b = g2i/(63*512); int r = g2i - b*63*512;
        int t = r>>9; int e = r&511;
        out[((size_t)b*TT + t)*DIMM + e] = 0.f;
    } else if (g < QN+ON+GN){
        int g3 = g - QN - ON;
        int b = g3/(63*HH); int r = g3 - b*63*HH;
        int j = 8129 + (r>>3); int hh = r&7;
        gate_t[((size_t)b*TT + j)*HH + hh] = 0.f;
    }
}

// ---------------------------------------------------------------------------
extern "C" void kernel_launch(void* const* d_in, const int* in_sizes, int n_in,
                              void* d_out, int out_size, void* d_ws, size_t ws_size,
                              hipStream_t stream)
{
    (void)in_sizes; (void)n_in; (void)out_size; (void)ws_size;
    const float* seq    = (const float*)d_in[0];
    const float* w1     = (const float*)d_in[1];
    const float* w2     = (const float*)d_in[2];
    const float* Wq     = (const float*)d_in[3];
    const float* Wkv    = (const float*)d_in[4];
    const float* Wstep  = (const float*)d_in[5];
    const float* Wmom   = (const float*)d_in[6];
    const float* Wdecay = (const float*)d_in[7];
    const float* Wgate  = (const float*)d_in[8];
    const float* Wcomb  = (const float*)d_in[9];
    const float* gamma  = (const float*)d_in[10];
    float* out = (float*)d_out;

    float* scale = (float*)d_ws;          // 32768
    float* lr_t  = scale + 32768;         // 262144  [b][t][h]
    float* gate_t= lr_t + 262144;         // 262144  [b][j][h]
    float* mom   = gate_t + 262144;       // 4096
    float* dec   = mom + 4096;            // 4096
    uint16_t* btkv = (uint16_t*)(dec + 4096);  // 1024*512 bf16 [n][k]
    uint16_t* btq  = btkv + 1024*512;          // 512*512
    uint16_t* btc  = btq  + 512*512;           // 512*512
    uint16_t* kb = btc + 512*512;            // 16777216 bf16 (q reuses after k_grad)
    uint16_t* vb = kb + 16777216;            // 16777216 bf16 (y reuses after k_retrieve)
    uint16_t* g1 = vb + 16777216;            // 16777216 bf16 g1^T (scan -> upd1^T)
    uint16_t* g2 = g1 + 16777216;            // 16777216 bf16 g2^T (scan -> upd2^T)
    uint16_t* sbf = g1;                      // [32768][512] bf16 seq*scale —
                                             // aliases g1 (dead until k_grad)
    uint16_t* wsg = g2;                      // [16][512] bf16 [Wstep|Wgate]^T —
                                             // aliases g2 (dead until k_grad)
    // wpack aliases btkv (dead after k_gemm<0>; read by k_grad + k_retrieve)
    uint16_t* w1t_bf = btkv;                 // [64][64] bf16 w1^T
    uint16_t* w2t_bf = btkv + 4096;          // [64][64] bf16 w2^T
    uint16_t* w2b_bf = btkv + 8192;          // [64][64] bf16 w2
    float*    w1t_f  = (float*)(btkv + 16384);  // [64][64] f32 w1^T
    float*    w2t_f  = w1t_f + 4096;            // [64][64] f32 w2^T

    k_transpose<<<dim3(32,16), 256, 0, stream>>>(Wkv,   btkv, 1024);
    k_transpose<<<dim3(16,16), 256, 0, stream>>>(Wq,    btq,  512);
    k_transpose<<<dim3(16,16), 256, 0, stream>>>(Wcomb, btc,  512);
    k_pack_wsg  <<<32, 256, 0, stream>>>(Wstep, Wgate, wsg);
    k_scale     <<<8192, 256, 0, stream>>>(seq, scale, sbf);
    k_lr_gate   <<<256, 256, 0, stream>>>(sbf, wsg, lr_t, gate_t);
    k_chunk_gates<<<BB*NN, 512, 0, stream>>>(seq, scale, Wmom, Wdecay, mom, dec);
    k_gemm_mfma<0><<<dim3(8, 256), 256, 0, stream>>>(sbf, btkv, nullptr, kb, vb);
    k_pack_w <<<1, 256, 0, stream>>>(w1, w2, w1t_bf, w2t_bf, w2b_bf, w1t_f, w2t_f);
    k_grad   <<<BHH*NN, 256, 0, stream>>>(kb, vb, lr_t, w1t_bf, w2t_bf, w2b_bf, g1, g2);
    k_scan   <<<256, 256, 0, stream>>>(g1, g2, mom, dec);
    k_gemm_mfma<1><<<dim3(4, 256), 256, 0, stream>>>(seq, btq, scale, kb /*q*/, nullptr);
    k_zero   <<<1017, 256, 0, stream>>>(kb /*q*/, out, gate_t);
    k_retrieve<<<BHH*NN, 256, 0, stream>>>(kb /*q*/, g1, g2, w1t_f, w2t_f, gamma, gate_t, vb /*y*/);
    k_gemm_mfma<2><<<dim3(4, 256), 256, 0, stream>>>(vb /*y*/, btc, nullptr, out, nullptr);
}

// Round 10
// 371.745 us; speedup vs baseline: 1.0196x; 1.0196x over previous
//
#include <hip/hip_runtime.h>
#include <cstdint>

// NeuralMemory forward. MFMA bf16 for big GEMMs + per-chunk MLP grad/retrieve.
// Shapes (fixed): B=4 T=8192 DIM=512 H=8 D=64 C=64 N=128 BH=32
// R5: split k_norm_scale -> k_scale + MFMA k_lr_gate (559->468us).
// R6/R7: sbf=bf16(seq*scale) staged once; XCD-chunk swizzle (468->405us).
// R8: k_grad conflict/VALU cleanup (405->380us).
// R9/R10: B-direct-from-L2 REGRESSED for the deep gemm loop.
// R11: revert gemm to R8; k_scan 4-lane+prefetch (380->378us).
// R12/R13: gemm staging via global_load_lds w16 + XOR swizzle — bank
//     conflicts 4.19M->0, gemm<0> 58->55us (379us total).
// R14: k_grad occupancy fix: LDS 8 slots->5 (74->46KB, 2->3 blocks/CU).
//     w1^T/w2^T/w2 A-fragments read DIRECTLY from global (L1-resident 8KB
//     each, k_lr_gate-proven one-shot pattern); slot reuse by liveness
//     (dxA<-kcB, dxB<-vB in-place, dx1T<-hB). Bit-identical math.
#define EPS     1.1920929e-07f
#define MAX_LR  0.01f
#define BB      4
#define TT      8192
#define DIMM    512
#define HH      8
#define DD      64
#define CC      64
#define NN      128
#define BHH     32
#define LDSP    72      // LDS row stride (bf16) for padded layouts

typedef __attribute__((ext_vector_type(8))) short short8;
typedef __attribute__((ext_vector_type(4))) float f32x4;

__device__ __forceinline__ float sigmoidf_(float x){ return 1.0f/(1.0f+__expf(-x)); }
__device__ __forceinline__ float bf2f(uint32_t lo16){ return __uint_as_float(lo16<<16); }
__device__ __forceinline__ uint16_t f2bf(float f){
    uint32_t x = __float_as_uint(f);
    return (uint16_t)((x + 0x7fffu + ((x>>16)&1u)) >> 16);   // RNE
}
__device__ __forceinline__ uint32_t pk2(float a, float b){
    return (uint32_t)f2bf(a) | ((uint32_t)f2bf(b)<<16);
}
// async global->LDS, 16B/lane. LDS dest = wave-uniform base + lane*16.
__device__ __forceinline__ void gload_lds16(const uint16_t* g, uint16_t* l){
    __builtin_amdgcn_global_load_lds(
        (const __attribute__((address_space(1))) unsigned int*)g,
        (__attribute__((address_space(3))) unsigned int*)l, 16, 0, 0);
}

// 64x64x64 GEMM slice on padded-72 LDS (A and B both LDS).
__device__ __forceinline__ void gemm64(const uint16_t* A, const uint16_t* B,
                                       int strip, int q, int col, f32x4* acc)
{
    #pragma unroll
    for (int ks=0; ks<64; ks+=32){
        short8 af = *(const short8*)&A[(strip*16+col)*LDSP + ks + q*8];
        #pragma unroll
        for (int nt=0;nt<4;nt++){
            short8 bf = *(const short8*)&B[(nt*16+col)*LDSP + ks + q*8];
            acc[nt] = __builtin_amdgcn_mfma_f32_16x16x32_bf16(af, bf, acc[nt], 0,0,0);
        }
    }
}

// Variant: A-fragments read DIRECTLY from a [64][64] bf16 GLOBAL matrix
// (L1/L2-resident weights). B from padded LDS.
__device__ __forceinline__ void gemm64g(const uint16_t* __restrict__ Ag,
                                        const uint16_t* B,
                                        int strip, int q, int col, f32x4* acc)
{
    #pragma unroll
    for (int ks=0; ks<64; ks+=32){
        short8 af = *(const short8*)&Ag[(strip*16+col)*DD + ks + q*8];
        #pragma unroll
        for (int nt=0;nt<4;nt++){
            short8 bf = *(const short8*)&B[(nt*16+col)*LDSP + ks + q*8];
            acc[nt] = __builtin_amdgcn_mfma_f32_16x16x32_bf16(af, bf, acc[nt], 0,0,0);
        }
    }
}

// ---------------------------------------------------------------------------
// K1a: wave-per-row rmsnorm scale + bf16(seq*scale) stream-out.
// ---------------------------------------------------------------------------
__global__ __launch_bounds__(256) void k_scale(
    const float* __restrict__ seq, float* __restrict__ scale,
    uint16_t* __restrict__ sbf)
{
    int wave = threadIdx.x >> 6, lane = threadIdx.x & 63;
    int row = blockIdx.x*4 + wave;          // b*T + t
    const float4* sp = (const float4*)&seq[(size_t)row*DIMM + lane*8];
    float4 x0 = sp[0], x1 = sp[1];
    float ss = x0.x*x0.x + x0.y*x0.y + x0.z*x0.z + x0.w*x0.w
             + x1.x*x1.x + x1.y*x1.y + x1.z*x1.z + x1.w*x1.w;
    #pragma unroll
    for (int o=32;o;o>>=1) ss += __shfl_xor(ss,o,64);
    float sc = rsqrtf(ss*(1.0f/DIMM)+EPS);
    if (lane==0) scale[row] = sc;
    uint4 v;
    v.x = pk2(x0.x*sc, x0.y*sc);
    v.y = pk2(x0.z*sc, x0.w*sc);
    v.z = pk2(x1.x*sc, x1.y*sc);
    v.w = pk2(x1.z*sc, x1.w*sc);
    *(uint4*)&sbf[(size_t)row*DIMM + lane*8] = v;
}

// ---------------------------------------------------------------------------
// K1b-prep: pack [Wstep|Wgate] -> bf16 B^T rows [16][512] (row = out col).
// ---------------------------------------------------------------------------
__global__ __launch_bounds__(256) void k_pack_wsg(
    const float* __restrict__ Wstep, const float* __restrict__ Wgate,
    uint16_t* __restrict__ wsg)
{
    int g = blockIdx.x*256 + threadIdx.x;   // 8192 total
    int j = g >> 9, k = g & 511;
    float v = (j < HH) ? Wstep[k*HH + j] : Wgate[k*HH + (j-HH)];
    wsg[j*DIMM + k] = f2bf(v);
}

// ---------------------------------------------------------------------------
// K1c: precompute w1^T/w2^T (bf16 + f32) and w2 bf16 row-major. One block.
// ---------------------------------------------------------------------------
__global__ __launch_bounds__(256) void k_pack_w(
    const float* __restrict__ w1, const float* __restrict__ w2,
    uint16_t* __restrict__ w1t_bf, uint16_t* __restrict__ w2t_bf,
    uint16_t* __restrict__ w2b_bf, float* __restrict__ w1t_f,
    float* __restrict__ w2t_f)
{
    __shared__ float t1[64][65];
    __shared__ float t2[64][65];
    int tx = threadIdx.x & 63, ty = threadIdx.x >> 6;   // 64 x 4
    #pragma unroll
    for (int i=0;i<16;i++){
        int row = ty*16 + i;
        float v1 = w1[row*DD + tx];
        float v2 = w2[row*DD + tx];
        t1[row][tx] = v1;
        t2[row][tx] = v2;
        w2b_bf[row*DD + tx] = f2bf(v2);
    }
    __syncthreads();
    #pragma unroll
    for (int i=0;i<16;i++){
        int row = ty*16 + i;
        float v1 = t1[tx][row];     // w1[p=tx][d1=row] -> w1t[row][tx]
        float v2 = t2[tx][row];
        w1t_f[row*DD + tx] = v1;
        w1t_bf[row*DD + tx] = f2bf(v1);
        w2t_f[row*DD + tx] = v2;
        w2t_bf[row*DD + tx] = f2bf(v2);
    }
}

// ---------------------------------------------------------------------------
// K1b: lr/gate thin GEMM via MFMA: (32768 x 512) @ (512 x 16).
// ---------------------------------------------------------------------------
__global__ __launch_bounds__(256) void k_lr_gate(
    const uint16_t* __restrict__ sbf, const uint16_t* __restrict__ wsg,
    float* __restrict__ lr_t, float* __restrict__ gate_t)
{
    __shared__ uint16_t Asl[128][LDSP];
    int tid = threadIdx.x;
    int w = tid>>6, lane = tid&63, q = lane>>4, col = lane&15;
    int m0 = blockIdx.x*128;

    f32x4 acc[2];
    acc[0] = (f32x4){0.f,0.f,0.f,0.f};
    acc[1] = (f32x4){0.f,0.f,0.f,0.f};

    for (int k0=0;k0<DIMM;k0+=64){
        #pragma unroll
        for (int s=0;s<4;s++){
            int seg = s*256 + tid;
            int row = seg>>3, kk = seg&7;
            uint4 v = *(const uint4*)&sbf[(size_t)(m0+row)*DIMM + k0 + kk*8];
            *(uint4*)&Asl[row][kk*8] = v;
        }
        __syncthreads();
        #pragma unroll
        for (int ks=0;ks<64;ks+=32){
            short8 bf = *(const short8*)&wsg[(size_t)col*DIMM + k0 + ks + q*8];
            #pragma unroll
            for (int mt=0;mt<2;mt++){
                short8 af = *(const short8*)&Asl[w*32 + mt*16 + col][ks + q*8];
                acc[mt] = __builtin_amdgcn_mfma_f32_16x16x32_bf16(af, bf, acc[mt], 0,0,0);
            }
        }
        __syncthreads();
    }

    #pragma unroll
    for (int mt=0;mt<2;mt++){
        #pragma unroll
        for (int reg=0;reg<4;reg++){
            int m = m0 + w*32 + mt*16 + q*4 + reg;
            int b = m>>13, t = m&8191;
            float val = sigmoidf_(acc[mt][reg]);
            if (col < HH){
                lr_t[(size_t)m*HH + col] = val*MAX_LR;
            } else {
                int j = t-63;
                if (j >= 0)
                    gate_t[((size_t)b*TT + j)*HH + (col-HH)] = val;
            }
        }
    }
}

// ---------------------------------------------------------------------------
// K2: chunk means (unchanged — f32 path kept for gate precision)
// ---------------------------------------------------------------------------
__global__ __launch_bounds__(512) void k_chunk_gates(
    const float* __restrict__ seq, const float* __restrict__ scale,
    const float* __restrict__ Wmom, const float* __restrict__ Wdecay,
    float* __restrict__ mom, float* __restrict__ dec)
{
    int blk = blockIdx.x;              // b*N + n
    int b = blk>>7, n = blk&127;
    int tid = threadIdx.x;
    __shared__ float scl[CC];
    if (tid < CC) scl[tid] = scale[b*TT + n*CC + tid];
    __syncthreads();
    size_t base = ((size_t)b*TT + n*CC)*DIMM + tid;
    float acc=0.f;
    #pragma unroll 8
    for (int j=0;j<CC;j++) acc += seq[base + (size_t)j*DIMM]*scl[j];
    __shared__ float sm[DIMM];
    sm[tid] = acc*(1.0f/CC);
    __syncthreads();
    int wid = tid>>6, lane = tid&63;
    float d1=0.f, d2=0.f;
    #pragma unroll
    for (int i=0;i<8;i++){
        int idx=i*64+lane; float sv=sm[idx];
        d1 += sv*Wmom[idx*HH+wid];
        d2 += sv*Wdecay[idx*HH+wid];
    }
    #pragma unroll
    for (int o=32;o;o>>=1){ d1+=__shfl_down(d1,o,64); d2+=__shfl_down(d2,o,64); }
    if (lane==0){
        mom[(b*HH+wid)*NN + n] = sigmoidf_(d1);
        dec[(b*HH+wid)*NN + n] = sigmoidf_(d2);
    }
}

// ---------------------------------------------------------------------------
// K3a: transpose+convert B matrix (unchanged)
// ---------------------------------------------------------------------------
__global__ __launch_bounds__(256) void k_transpose(
    const float* __restrict__ in, uint16_t* __restrict__ out, int Ncols)
{
    __shared__ float tile[32][33];
    int bx = blockIdx.x*32;   // n
    int by = blockIdx.y*32;   // k
    int lx = threadIdx.x&31, ly = threadIdx.x>>5;   // 32 x 8
    #pragma unroll
    for (int r=0;r<4;r++)
        tile[ly+8*r][lx] = in[(size_t)(by+ly+8*r)*Ncols + bx+lx];
    __syncthreads();
    #pragma unroll
    for (int r=0;r<4;r++)
        out[(size_t)(bx+ly+8*r)*DIMM + by+lx] = f2bf(tile[lx][ly+8*r]);
}

// ---------------------------------------------------------------------------
// K3: MFMA GEMM (R12 form). MODE 0/2: A+B via global_load_lds into linear
// [128][64] LDS, XOR swizzle group^=(row&7) on global source + reads.
// MODE 1: A f32*scale register-converted into padded [128][72].
// ---------------------------------------------------------------------------
template<int MODE>
__global__ __launch_bounds__(256) void k_gemm_mfma(
    const void* __restrict__ Av, const uint16_t* __restrict__ Bt,
    const float* __restrict__ scale, void* __restrict__ out0,
    void* __restrict__ out1)
{
    __shared__ uint16_t Asl[128*72];   // MODE1: padded 72; MODE0/2: linear 64
    __shared__ uint16_t Bsl[128*64];   // linear 64, swizzled
    __shared__ float sscale[128];
    int tid = threadIdx.x;
    int wave = tid>>6, lane = tid&63;
    int q = lane>>4, col = lane&15;
    // bijective XCD swizzle: hw dispatch is x-fastest, XCD = bid%8.
    int bid = blockIdx.y*gridDim.x + blockIdx.x;
    int xcd = bid & 7, local = bid >> 3;
    int mper = gridDim.y >> 3;                  // m-tiles per XCD
    int m0 = (xcd*mper + local/gridDim.x)*128;
    int n0 = (local%gridDim.x)*128;
    int m_off = (wave&1)*64, n_off = (wave>>1)*64;

    if (MODE==1){
        if (tid<128) sscale[tid] = scale[m0+tid];
        __syncthreads();
    }

    f32x4 acc[4][4];
    #pragma unroll
    for (int i=0;i<4;i++)
        #pragma unroll
        for (int j=0;j<4;j++) acc[i][j] = (f32x4){0.f,0.f,0.f,0.f};

    int srow = wave*32 + (lane>>3);   // staging row (per lane), + s*8
    int sgs  = lane&7;                // staging group slot

    for (int k0=0;k0<DIMM;k0+=64){
        if (MODE!=1){
            const uint16_t* A = (const uint16_t*)Av;
            #pragma unroll
            for (int s=0;s<4;s++){
                int r = srow + s*8;
                gload_lds16(&A[(size_t)(m0+r)*DIMM + k0 + ((sgs ^ (r&7))<<3)],
                            &Asl[(wave*32 + s*8)*64]);
            }
        } else {
            const float* A = (const float*)Av;
            #pragma unroll
            for (int s=0;s<4;s++){
                int seg = s*256 + tid;
                int row = seg>>3, kk = seg&7;
                float sc = sscale[row];
                const float4* ap = (const float4*)&A[(size_t)(m0+row)*DIMM + k0 + kk*8];
                float4 a0 = ap[0], a1 = ap[1];
                uint4 v;
                v.x = pk2(a0.x*sc, a0.y*sc);
                v.y = pk2(a0.z*sc, a0.w*sc);
                v.z = pk2(a1.x*sc, a1.y*sc);
                v.w = pk2(a1.z*sc, a1.w*sc);
                *(uint4*)&Asl[row*72 + kk*8] = v;
            }
        }
        #pragma unroll
        for (int s=0;s<4;s++){
            int r = srow + s*8;
            gload_lds16(&Bt[(size_t)(n0+r)*DIMM + k0 + ((sgs ^ (r&7))<<3)],
                        &Bsl[(wave*32 + s*8)*64]);
        }
        __syncthreads();
        #pragma unroll
        for (int ks=0;ks<64;ks+=32){
            short8 af[4], bf[4];
            int g = q + (ks>>3);
            #pragma unroll
            for (int mt=0;mt<4;mt++){
                int r = m_off + mt*16 + col;
                if (MODE==1)
                    af[mt] = *(const short8*)&Asl[r*72 + ks + q*8];
                else
                    af[mt] = *(const short8*)&Asl[r*64 + ((g ^ (r&7))<<3)];
            }
            #pragma unroll
            for (int nt=0;nt<4;nt++){
                int rb = n_off + nt*16 + col;
                bf[nt] = *(const short8*)&Bsl[rb*64 + ((g ^ (rb&7))<<3)];
            }
            #pragma unroll
            for (int mt=0;mt<4;mt++)
                #pragma unroll
                for (int nt=0;nt<4;nt++)
                    acc[mt][nt] = __builtin_amdgcn_mfma_f32_16x16x32_bf16(
                        af[mt], bf[nt], acc[mt][nt], 0, 0, 0);
        }
        __syncthreads();
    }

    #pragma unroll
    for (int mt=0;mt<4;mt++){
        #pragma unroll
        for (int reg=0;reg<4;reg++){
            int m = m0 + m_off + mt*16 + q*4 + reg;
            int b = m>>13, t = m&8191;
            if (MODE==0){
                #pragma unroll
                for (int nt=0;nt<4;nt++){
                    int e = n0 + n_off + nt*16 + col;
                    uint16_t* basep = (uint16_t*)((e<512) ? out0 : out1);
                    int ee = e & 511;
                    int h = ee>>6, dk = ee&63;
                    basep[((size_t)(b*HH+h)*TT + t)*DD + dk] = f2bf(acc[mt][nt][reg]);
                }
            } else if (MODE==1){
                int j = t-63;
                if (j>=0){
                    #pragma unroll
                    for (int nt=0;nt<4;nt++){
                        int e = n0 + n_off + nt*16 + col;
                        int h = e>>6, dk = e&63;
                        ((uint16_t*)out0)[((size_t)(b*HH+h)*TT + j)*DD + dk] = f2bf(acc[mt][nt][reg]);
                    }
                }
            } else {
                int tp = t + 63;
                if (tp < TT){
                    #pragma unroll
                    for (int nt=0;nt<4;nt++){
                        int e = n0 + n_off + nt*16 + col;
                        ((float*)out0)[((size_t)b*TT + tp)*DIMM + e] = acc[mt][nt][reg];
                    }
                }
            }
        }
    }
}

// ---------------------------------------------------------------------------
// K4: per-chunk MLP gradient via MFMA. One block per (bh,n), 4 waves.
// R14: 5 LDS slots (46KB -> 3 blocks/CU); weight A-operands read directly
// from global (L1-resident). Slot reuse: dxA<-kcB, dxB<-vB (in-place),
// dx1T<-hB. Swapped-operand scheme (R8). Outputs -g1^T, -g2^T bf16.
// ---------------------------------------------------------------------------
__global__ __launch_bounds__(256) void k_grad(
    const uint16_t* __restrict__ kbuf, const uint16_t* __restrict__ vbuf,
    const float* __restrict__ lr_t, const uint16_t* __restrict__ w1t_bf,
    const uint16_t* __restrict__ w2t_bf, const uint16_t* __restrict__ w2b_bf,
    uint16_t* __restrict__ g1T, uint16_t* __restrict__ g2T)
{
    __shared__ uint16_t lds[5*64*LDSP];
    __shared__ float lr_sh[64];
    uint16_t* kcB  = lds + 0*64*LDSP;   // G1 B operand -> dxA after G2
    uint16_t* kcT  = lds + 1*64*LDSP;   // G5 B operand
    uint16_t* vB   = lds + 2*64*LDSP;   // G2 epilogue -> dxB (in-place)
    uint16_t* hA   = lds + 3*64*LDSP;   // G3 B operand
    uint16_t* hB   = lds + 4*64*LDSP;   // G2 B operand -> dx1T after G4
    uint16_t* dxA  = kcB;
    uint16_t* dxB  = vB;
    uint16_t* dx1T = hB;

    int bhn = blockIdx.x;
    int bh = bhn>>7, n = bhn&127;
    int b = bh>>3, h = bh&7;
    int tid = threadIdx.x, tx = tid&15, ty = tid>>4;
    int w = tid>>6, lane = tid&63, q = lane>>4, col = lane&15;
    size_t cbase = ((size_t)bh*TT + n*CC)*DD;

    // ---- stage kc (both layouts) + v ----
    #pragma unroll
    for (int r=0;r<4;r++){
        int row = ty*4+r;
        ushort4 k4 = *(const ushort4*)&kbuf[cbase + row*DD + tx*4];
        *(ushort4*)&kcB[row*LDSP + tx*4] = k4;
        kcT[(tx*4+0)*LDSP + row] = k4.x;
        kcT[(tx*4+1)*LDSP + row] = k4.y;
        kcT[(tx*4+2)*LDSP + row] = k4.z;
        kcT[(tx*4+3)*LDSP + row] = k4.w;
        ushort4 v4 = *(const ushort4*)&vbuf[cbase + row*DD + tx*4];
        *(ushort4*)&vB[row*LDSP + tx*4] = v4;
    }
    if (tid < 64) lr_sh[tid] = lr_t[((size_t)b*TT + n*CC + tid)*HH + h];
    __syncthreads();

    // ---- G1 (swapped): x1^T = (kc @ w1)^T. A = w1^T from GLOBAL ----
    f32x4 a1[4];
    #pragma unroll
    for (int i=0;i<4;i++) a1[i]=(f32x4){0.f,0.f,0.f,0.f};
    gemm64g(w1t_bf, kcB, w, q, col, a1);
    float sg[16], hr[16];
    #pragma unroll
    for (int nt=0;nt<4;nt++)
        #pragma unroll
        for (int reg=0;reg<4;reg++){
            int idx = nt*4+reg;
            float x = a1[nt][reg];
            float sgm = sigmoidf_(x);
            sg[idx]=sgm; hr[idx]=x*sgm;
            int d1 = w*16 + q*4 + reg;
            int token = nt*16 + col;
            uint16_t hv = f2bf(x*sgm);
            hA[d1*LDSP + token] = hv;      // natural
            hB[token*LDSP + d1] = hv;      // scatter
        }
    __syncthreads();

    // ---- G2 (swapped): x2^T = (h @ w2)^T; A = w2^T GLOBAL.
    //      dx2 = (2/D)*lr*(x2 - v); dxA -> kcB slot, dxB -> vB in-place ----
    f32x4 a2[4];
    #pragma unroll
    for (int i=0;i<4;i++) a2[i]=(f32x4){0.f,0.f,0.f,0.f};
    gemm64g(w2t_bf, hB, w, q, col, a2);
    __syncthreads();   // all kcB(G1)/hB(G2) reads done before slot reuse
    #pragma unroll
    for (int nt=0;nt<4;nt++)
        #pragma unroll
        for (int reg=0;reg<4;reg++){
            int d2 = w*16 + q*4 + reg;
            int token = nt*16 + col;
            float vv = bf2f(vB[token*LDSP + d2]);
            float dx = (2.0f/DD)*lr_sh[token]*(a2[nt][reg]-vv);
            uint16_t dv = f2bf(dx);
            dxA[d2*LDSP + token] = dv;     // kcB slot (dead)
            dxB[token*LDSP + d2] = dv;     // vB slot, same index as read
        }
    __syncthreads();

    // ---- G3: g2^T = dx2^T @ h  (rows=d2 strip, cols=d1) ----
    f32x4 a3[4];
    #pragma unroll
    for (int i=0;i<4;i++) a3[i]=(f32x4){0.f,0.f,0.f,0.f};
    gemm64(dxA, hA, w, q, col, a3);
    // ---- G4 (swapped): dh^T = w2 @ dx2^T; A = w2 GLOBAL ----
    f32x4 a4[4];
    #pragma unroll
    for (int i=0;i<4;i++) a4[i]=(f32x4){0.f,0.f,0.f,0.f};
    gemm64g(w2b_bf, dxB, w, q, col, a4);

    size_t gb = (size_t)bhn*4096;
    #pragma unroll
    for (int nt=0;nt<4;nt++)
        #pragma unroll
        for (int reg=0;reg<4;reg++){
            int d2 = w*16 + q*4 + reg;
            int d1 = nt*16 + col;
            g2T[gb + d2*DD + d1] = f2bf(-a3[nt][reg]);
        }
    #pragma unroll
    for (int nt=0;nt<4;nt++)
        #pragma unroll
        for (int reg=0;reg<4;reg++){
            int idx = nt*4+reg;
            int d1 = w*16 + q*4 + reg;
            int token = nt*16 + col;
            float dsl = sg[idx] + hr[idx]*(1.f-sg[idx]);
            dx1T[d1*LDSP + token] = f2bf(a4[nt][reg]*dsl);   // hB slot (dead)
        }
    __syncthreads();

    // ---- G5: g1^T = dx1^T @ kc  (rows=d1 strip, cols=p) ----
    f32x4 a5[4];
    #pragma unroll
    for (int i=0;i<4;i++) a5[i]=(f32x4){0.f,0.f,0.f,0.f};
    gemm64(dx1T, kcT, w, q, col, a5);
    #pragma unroll
    for (int nt=0;nt<4;nt++)
        #pragma unroll
        for (int reg=0;reg<4;reg++){
            int d1 = w*16 + q*4 + reg;
            int p  = nt*16 + col;
            g1T[gb + d1*DD + p] = f2bf(-a5[nt][reg]);
        }
}

// ---------------------------------------------------------------------------
// K5: scans. 8B/thread (4 recurrence lanes) + 4-deep load prefetch.
// ---------------------------------------------------------------------------
__global__ __launch_bounds__(256) void k_scan(
    uint16_t* __restrict__ g1, uint16_t* __restrict__ g2,
    const float* __restrict__ mom, const float* __restrict__ dec)
{
    int blk = blockIdx.x;            // [0,256)
    int arr = blk>>7; int rem = blk&127;
    int bh = rem>>2; int eg = rem&3;
    int e4 = eg*1024 + threadIdx.x*4;
    uint16_t* gp = arr ? g2 : g1;
    __shared__ float smg[NN], sdc[NN];
    if (threadIdx.x < NN){
        smg[threadIdx.x] = mom[bh*NN+threadIdx.x];
        sdc[threadIdx.x] = 1.f - dec[bh*NN+threadIdx.x];
    }
    __syncthreads();
    size_t base = (size_t)bh*NN*4096 + e4;
    float m0=0.f,m1=0.f,m2=0.f,m3=0.f, u0=0.f,u1=0.f,u2=0.f,u3=0.f;
    uint2 p0 = *(const uint2*)&gp[base];
    uint2 p1 = *(const uint2*)&gp[base + 4096];
    uint2 p2 = *(const uint2*)&gp[base + 2*4096];
    uint2 p3 = *(const uint2*)&gp[base + 3*4096];
    for (int t=0; t<NN; t+=4){
        uint2 c0=p0, c1=p1, c2=p2, c3=p3;
        if (t+4 < NN){                       // uniform branch
            p0 = *(const uint2*)&gp[base + (size_t)(t+4)*4096];
            p1 = *(const uint2*)&gp[base + (size_t)(t+5)*4096];
            p2 = *(const uint2*)&gp[base + (size_t)(t+6)*4096];
            p3 = *(const uint2*)&gp[base + (size_t)(t+7)*4096];
        }
        #pragma unroll
        for (int j=0;j<4;j++){
            uint2 c = (j==0)?c0:(j==1)?c1:(j==2)?c2:c3;
            float g = smg[t+j], d = sdc[t+j];
            float v0 = bf2f(c.x&0xffffu), v1 = bf2f(c.x>>16);
            float v2 = bf2f(c.y&0xffffu), v3 = bf2f(c.y>>16);
            m0 = fmaf(g,m0,v0); u0 = fmaf(d,u0,m0);
            m1 = fmaf(g,m1,v1); u1 = fmaf(d,u1,m1);
            m2 = fmaf(g,m2,v2); u2 = fmaf(d,u2,m2);
            m3 = fmaf(g,m3,v3); u3 = fmaf(d,u3,m3);
            uint2 r; r.x = pk2(u0,u1); r.y = pk2(u2,u3);
            *(uint2*)&gp[base + (size_t)(t+j)*4096] = r;
        }
    }
}

// ---------------------------------------------------------------------------
// K6: retrieve via MFMA. One block per (bh,n), 4 waves.
// ---------------------------------------------------------------------------
__global__ __launch_bounds__(256) void k_retrieve(
    const uint16_t* __restrict__ qbuf, const uint16_t* __restrict__ u1T,
    const uint16_t* __restrict__ u2T, const float* __restrict__ w1Tf,
    const float* __restrict__ w2Tf, const float* __restrict__ gamma,
    const float* __restrict__ gate_t, uint16_t* __restrict__ y)
{
    __shared__ uint16_t qc[64*LDSP];
    __shared__ uint16_t W1s[64*LDSP];   // (w1+u1)^T rows: [d1][p]
    __shared__ uint16_t W2s[64*LDSP];   // (w2+u2)^T rows: [d2][d1]
    __shared__ uint16_t hB[64*LDSP];    // h rows: [token][d1]
    __shared__ float gate_sh[64], gam_sh[64];
    int bhn = blockIdx.x;
    int bh = bhn>>7, n = bhn&127;
    int b = bh>>3, h = bh&7;
    int tid = threadIdx.x, tx = tid&15, ty = tid>>4;
    int w = tid>>6, lane = tid&63, q = lane>>4, col = lane&15;
    size_t cbase = ((size_t)bh*TT + n*CC)*DD;
    size_t ub = (size_t)bhn*4096;

    #pragma unroll
    for (int r=0;r<4;r++){
        int row = ty*4+r;     // d_out index for W staging; token for qc
        *(ushort4*)&qc[row*LDSP + tx*4] =
            *(const ushort4*)&qbuf[cbase + row*DD + tx*4];
        ushort4 u14 = *(const ushort4*)&u1T[ub + row*DD + tx*4];
        float4 w1v = *(const float4*)&w1Tf[row*DD + tx*4];
        ushort4 s1;
        s1.x = f2bf(w1v.x + bf2f(u14.x));
        s1.y = f2bf(w1v.y + bf2f(u14.y));
        s1.z = f2bf(w1v.z + bf2f(u14.z));
        s1.w = f2bf(w1v.w + bf2f(u14.w));
        *(ushort4*)&W1s[row*LDSP + tx*4] = s1;
        ushort4 u24 = *(const ushort4*)&u2T[ub + row*DD + tx*4];
        float4 w2v = *(const float4*)&w2Tf[row*DD + tx*4];
        ushort4 s2;
        s2.x = f2bf(w2v.x + bf2f(u24.x));
        s2.y = f2bf(w2v.y + bf2f(u24.y));
        s2.z = f2bf(w2v.z + bf2f(u24.z));
        s2.w = f2bf(w2v.w + bf2f(u24.w));
        *(ushort4*)&W2s[row*LDSP + tx*4] = s2;
    }
    if (tid < 64){
        gate_sh[tid] = gate_t[((size_t)b*TT + n*CC + tid)*HH + h];
        gam_sh[tid]  = gamma[h*DD + tid];
    }
    __syncthreads();

    // G1: x1 = qc @ (w1+u1); h = silu
    f32x4 a1[4];
    #pragma unroll
    for (int i=0;i<4;i++) a1[i]=(f32x4){0.f,0.f,0.f,0.f};
    gemm64(qc, W1s, w, q, col, a1);
    #pragma unroll
    for (int nt=0;nt<4;nt++)
        #pragma unroll
        for (int reg=0;reg<4;reg++){
            float x = a1[nt][reg];
            int token = w*16 + q*4 + reg;
            int d1 = nt*16 + col;
            hB[token*LDSP + d1] = f2bf(x*sigmoidf_(x));
        }
    __syncthreads();

    // G2: x = h @ (w2+u2); rmsnorm(d=64) * (1+gamma) * gate -> y
    f32x4 a2[4];
    #pragma unroll
    for (int i=0;i<4;i++) a2[i]=(f32x4){0.f,0.f,0.f,0.f};
    gemm64(hB, W2s, w, q, col, a2);
    #pragma unroll
    for (int reg=0;reg<4;reg++){
        float p = 0.f;
        #pragma unroll
        for (int nt=0;nt<4;nt++) p += a2[nt][reg]*a2[nt][reg];
        p += __shfl_xor(p,1,64);
        p += __shfl_xor(p,2,64);
        p += __shfl_xor(p,4,64);
        p += __shfl_xor(p,8,64);
        float sclv = rsqrtf(p*(1.0f/DD)+EPS);
        int token = w*16 + q*4 + reg;
        float gt = gate_sh[token];
        size_t yb = ((size_t)b*TT + n*CC + token)*DIMM + h*DD;
        #pragma unroll
        for (int nt=0;nt<4;nt++){
            int d2 = nt*16 + col;
            y[yb + d2] = f2bf(a2[nt][reg]*sclv*(1.f+gam_sh[d2])*gt);
        }
    }
}

// ---------------------------------------------------------------------------
// K7: zero pads (unchanged)
// ---------------------------------------------------------------------------
__global__ __launch_bounds__(256) void k_zero(
    uint16_t* __restrict__ qbuf, float* __restrict__ out, float* __restrict__ gate_t)
{
    int g = blockIdx.x*256 + threadIdx.x;
    const int QN = BHH*63*DD;          // 129024
    const int ON = BB*63*DIMM;         // 129024
    const int GN = BB*63*HH;           // 2016
    if (g < QN){
        int bh = g/4032; int r = g - bh*4032;
        int j = 8129 + (r>>6); int dk = r&63;
        qbuf[((size_t)bh*TT + j)*DD + dk] = 0;
    } else if (g < QN+ON){
        int g2i = g - QN;
        int b = g2i/(63*512); int r = g2i - b*63*512;
        int t = r>>9; int e = r&511;
        out[((size_t)b*TT + t)*DIMM + e] = 0.f;
    } else if (g < QN+ON+GN){
        int g3 = g - QN - ON;
        int b = g3/(63*HH); int r = g3 - b*63*HH;
        int j = 8129 + (r>>3); int hh = r&7;
        gate_t[((size_t)b*TT + j)*HH + hh] = 0.f;
    }
}

// ---------------------------------------------------------------------------
extern "C" void kernel_launch(void* const* d_in, const int* in_sizes, int n_in,
                              void* d_out, int out_size, void* d_ws, size_t ws_size,
                              hipStream_t stream)
{
    (void)in_sizes; (void)n_in; (void)out_size; (void)ws_size;
    const float* seq    = (const float*)d_in[0];
    const float* w1     = (const float*)d_in[1];
    const float* w2     = (const float*)d_in[2];
    const float* Wq     = (const float*)d_in[3];
    const float* Wkv    = (const float*)d_in[4];
    const float* Wstep  = (const float*)d_in[5];
    const float* Wmom   = (const float*)d_in[6];
    const float* Wdecay = (const float*)d_in[7];
    const float* Wgate  = (const float*)d_in[8];
    const float* Wcomb  = (const float*)d_in[9];
    const float* gamma  = (const float*)d_in[10];
    float* out = (float*)d_out;

    float* scale = (float*)d_ws;          // 32768
    float* lr_t  = scale + 32768;         // 262144  [b][t][h]
    float* gate_t= lr_t + 262144;         // 262144  [b][j][h]
    float* mom   = gate_t + 262144;       // 4096
    float* dec   = mom + 4096;            // 4096
    uint16_t* btkv = (uint16_t*)(dec + 4096);  // 1024*512 bf16 [n][k]
    uint16_t* btq  = btkv + 1024*512;          // 512*512
    uint16_t* btc  = btq  + 512*512;           // 512*512
    uint16_t* kb = btc + 512*512;            // 16777216 bf16 (q reuses after k_grad)
    uint16_t* vb = kb + 16777216;            // 16777216 bf16 (y reuses after k_retrieve)
    uint16_t* g1 = vb + 16777216;            // 16777216 bf16 g1^T (scan -> upd1^T)
    uint16_t* g2 = g1 + 16777216;            // 16777216 bf16 g2^T (scan -> upd2^T)
    uint16_t* sbf = g1;                      // [32768][512] bf16 seq*scale —
                                             // aliases g1 (dead until k_grad)
    uint16_t* wsg = g2;                      // [16][512] bf16 [Wstep|Wgate]^T —
                                             // aliases g2 (dead until k_grad)
    // wpack aliases btkv (dead after k_gemm<0>; read by k_grad + k_retrieve)
    uint16_t* w1t_bf = btkv;                 // [64][64] bf16 w1^T
    uint16_t* w2t_bf = btkv + 4096;          // [64][64] bf16 w2^T
    uint16_t* w2b_bf = btkv + 8192;          // [64][64] bf16 w2
    float*    w1t_f  = (float*)(btkv + 16384);  // [64][64] f32 w1^T
    float*    w2t_f  = w1t_f + 4096;            // [64][64] f32 w2^T

    k_transpose<<<dim3(32,16), 256, 0, stream>>>(Wkv,   btkv, 1024);
    k_transpose<<<dim3(16,16), 256, 0, stream>>>(Wq,    btq,  512);
    k_transpose<<<dim3(16,16), 256, 0, stream>>>(Wcomb, btc,  512);
    k_pack_wsg  <<<32, 256, 0, stream>>>(Wstep, Wgate, wsg);
    k_scale     <<<8192, 256, 0, stream>>>(seq, scale, sbf);
    k_lr_gate   <<<256, 256, 0, stream>>>(sbf, wsg, lr_t, gate_t);
    k_chunk_gates<<<BB*NN, 512, 0, stream>>>(seq, scale, Wmom, Wdecay, mom, dec);
    k_gemm_mfma<0><<<dim3(8, 256), 256, 0, stream>>>(sbf, btkv, nullptr, kb, vb);
    k_pack_w <<<1, 256, 0, stream>>>(w1, w2, w1t_bf, w2t_bf, w2b_bf, w1t_f, w2t_f);
    k_grad   <<<BHH*NN, 256, 0, stream>>>(kb, vb, lr_t, w1t_bf, w2t_bf, w2b_bf, g1, g2);
    k_scan   <<<256, 256, 0, stream>>>(g1, g2, mom, dec);
    k_gemm_mfma<1><<<dim3(4, 256), 256, 0, stream>>>(seq, btq, scale, kb /*q*/, nullptr);
    k_zero   <<<1017, 256, 0, stream>>>(kb /*q*/, out, gate_t);
    k_retrieve<<<BHH*NN, 256, 0, stream>>>(kb /*q*/, g1, g2, w1t_f, w2t_f, gamma, gate_t, vb /*y*/);
    k_gemm_mfma<2><<<dim3(4, 256), 256, 0, stream>>>(vb /*y*/, btc, nullptr, out, nullptr);
}

// Round 11
// 357.702 us; speedup vs baseline: 1.0596x; 1.0393x over previous
//
#include <hip/hip_runtime.h>
#include <cstdint>

// NeuralMemory forward. MFMA bf16 for big GEMMs + per-chunk MLP grad/retrieve.
// Shapes (fixed): B=4 T=8192 DIM=512 H=8 D=64 C=64 N=128 BH=32
// R5: split k_norm_scale -> k_scale + MFMA k_lr_gate (559->468us).
// R6/R7: sbf=bf16(seq*scale) staged once; XCD-chunk swizzle (468->405us).
// R8: k_grad conflict/VALU cleanup (405->380us).
// R9/R10: B-direct-from-L2 REGRESSED for the deep gemm loop.
// R11: revert gemm to R8; k_scan 4-lane+prefetch (380->378us).
// R12/R13: gemm staging via global_load_lds w16 + XOR swizzle (379us).
// R14: k_grad LDS 8->5 slots, weights direct-from-global (371.7us).
// R15: (a) gemm<0> epilogue coalescing: C tile restaged via free Asl/Bsl
//     LDS -> dwordx4 stores at 128B granularity (was 64 scalar 2B stores).
//     (b) k_chunk_gates reads sbf (halve traffic, drop multiply).
//     (c) merge 5 prep kernels -> k_prep; wpack gets dedicated ws slot.
#define EPS     1.1920929e-07f
#define MAX_LR  0.01f
#define BB      4
#define TT      8192
#define DIMM    512
#define HH      8
#define DD      64
#define CC      64
#define NN      128
#define BHH     32
#define LDSP    72      // LDS row stride (bf16) for padded layouts

typedef __attribute__((ext_vector_type(8))) short short8;
typedef __attribute__((ext_vector_type(4))) float f32x4;

__device__ __forceinline__ float sigmoidf_(float x){ return 1.0f/(1.0f+__expf(-x)); }
__device__ __forceinline__ float bf2f(uint32_t lo16){ return __uint_as_float(lo16<<16); }
__device__ __forceinline__ uint16_t f2bf(float f){
    uint32_t x = __float_as_uint(f);
    return (uint16_t)((x + 0x7fffu + ((x>>16)&1u)) >> 16);   // RNE
}
__device__ __forceinline__ uint32_t pk2(float a, float b){
    return (uint32_t)f2bf(a) | ((uint32_t)f2bf(b)<<16);
}
// async global->LDS, 16B/lane. LDS dest = wave-uniform base + lane*16.
__device__ __forceinline__ void gload_lds16(const uint16_t* g, uint16_t* l){
    __builtin_amdgcn_global_load_lds(
        (const __attribute__((address_space(1))) unsigned int*)g,
        (__attribute__((address_space(3))) unsigned int*)l, 16, 0, 0);
}

// 64x64x64 GEMM slice on padded-72 LDS (A and B both LDS).
__device__ __forceinline__ void gemm64(const uint16_t* A, const uint16_t* B,
                                       int strip, int q, int col, f32x4* acc)
{
    #pragma unroll
    for (int ks=0; ks<64; ks+=32){
        short8 af = *(const short8*)&A[(strip*16+col)*LDSP + ks + q*8];
        #pragma unroll
        for (int nt=0;nt<4;nt++){
            short8 bf = *(const short8*)&B[(nt*16+col)*LDSP + ks + q*8];
            acc[nt] = __builtin_amdgcn_mfma_f32_16x16x32_bf16(af, bf, acc[nt], 0,0,0);
        }
    }
}

// Variant: A-fragments read DIRECTLY from a [64][64] bf16 GLOBAL matrix
// (L1/L2-resident weights). B from padded LDS.
__device__ __forceinline__ void gemm64g(const uint16_t* __restrict__ Ag,
                                        const uint16_t* B,
                                        int strip, int q, int col, f32x4* acc)
{
    #pragma unroll
    for (int ks=0; ks<64; ks+=32){
        short8 af = *(const short8*)&Ag[(strip*16+col)*DD + ks + q*8];
        #pragma unroll
        for (int nt=0;nt<4;nt++){
            short8 bf = *(const short8*)&B[(nt*16+col)*LDSP + ks + q*8];
            acc[nt] = __builtin_amdgcn_mfma_f32_16x16x32_bf16(af, bf, acc[nt], 0,0,0);
        }
    }
}

// ---------------------------------------------------------------------------
// K0: merged prep. blk<512: Wkv->btkv; <768: Wq->btq; <1024: Wcomb->btc;
// <1056: pack [Wstep|Wgate]->wsg; ==1056: pack w1^T/w2^T/w2.
// ---------------------------------------------------------------------------
__global__ __launch_bounds__(256) void k_prep(
    const float* __restrict__ Wkv, const float* __restrict__ Wq,
    const float* __restrict__ Wcomb, const float* __restrict__ Wstep,
    const float* __restrict__ Wgate, const float* __restrict__ w1,
    const float* __restrict__ w2,
    uint16_t* __restrict__ btkv, uint16_t* __restrict__ btq,
    uint16_t* __restrict__ btc, uint16_t* __restrict__ wsg,
    uint16_t* __restrict__ w1t_bf, uint16_t* __restrict__ w2t_bf,
    uint16_t* __restrict__ w2b_bf, float* __restrict__ w1t_f,
    float* __restrict__ w2t_f)
{
    __shared__ float tile[32][33];
    __shared__ float t1[64][65];
    __shared__ float t2[64][65];
    int blk = blockIdx.x;
    if (blk < 1024){
        const float* in; uint16_t* out; int Ncols; int i;
        if (blk < 512){ in=Wkv; out=btkv; Ncols=1024; i=blk; }
        else if (blk < 768){ in=Wq; out=btq; Ncols=512; i=blk-512; }
        else { in=Wcomb; out=btc; Ncols=512; i=blk-768; }
        int nx = Ncols>>5;
        int bx = (i % nx)*32, by = (i / nx)*32;
        int lx = threadIdx.x&31, ly = threadIdx.x>>5;   // 32 x 8
        #pragma unroll
        for (int r=0;r<4;r++)
            tile[ly+8*r][lx] = in[(size_t)(by+ly+8*r)*Ncols + bx+lx];
        __syncthreads();
        #pragma unroll
        for (int r=0;r<4;r++)
            out[(size_t)(bx+ly+8*r)*DIMM + by+lx] = f2bf(tile[lx][ly+8*r]);
    } else if (blk < 1056){
        int g = (blk-1024)*256 + threadIdx.x;   // 8192 total
        int j = g >> 9, k = g & 511;
        float v = (j < HH) ? Wstep[k*HH + j] : Wgate[k*HH + (j-HH)];
        wsg[j*DIMM + k] = f2bf(v);
    } else {
        int tx = threadIdx.x & 63, ty = threadIdx.x >> 6;   // 64 x 4
        #pragma unroll
        for (int i=0;i<16;i++){
            int row = ty*16 + i;
            float v1 = w1[row*DD + tx];
            float v2 = w2[row*DD + tx];
            t1[row][tx] = v1;
            t2[row][tx] = v2;
            w2b_bf[row*DD + tx] = f2bf(v2);
        }
        __syncthreads();
        #pragma unroll
        for (int i=0;i<16;i++){
            int row = ty*16 + i;
            float v1 = t1[tx][row];     // w1[p=tx][d1=row] -> w1t[row][tx]
            float v2 = t2[tx][row];
            w1t_f[row*DD + tx] = v1;
            w1t_bf[row*DD + tx] = f2bf(v1);
            w2t_f[row*DD + tx] = v2;
            w2t_bf[row*DD + tx] = f2bf(v2);
        }
    }
}

// ---------------------------------------------------------------------------
// K1a: wave-per-row rmsnorm scale + bf16(seq*scale) stream-out.
// ---------------------------------------------------------------------------
__global__ __launch_bounds__(256) void k_scale(
    const float* __restrict__ seq, float* __restrict__ scale,
    uint16_t* __restrict__ sbf)
{
    int wave = threadIdx.x >> 6, lane = threadIdx.x & 63;
    int row = blockIdx.x*4 + wave;          // b*T + t
    const float4* sp = (const float4*)&seq[(size_t)row*DIMM + lane*8];
    float4 x0 = sp[0], x1 = sp[1];
    float ss = x0.x*x0.x + x0.y*x0.y + x0.z*x0.z + x0.w*x0.w
             + x1.x*x1.x + x1.y*x1.y + x1.z*x1.z + x1.w*x1.w;
    #pragma unroll
    for (int o=32;o;o>>=1) ss += __shfl_xor(ss,o,64);
    float sc = rsqrtf(ss*(1.0f/DIMM)+EPS);
    if (lane==0) scale[row] = sc;
    uint4 v;
    v.x = pk2(x0.x*sc, x0.y*sc);
    v.y = pk2(x0.z*sc, x0.w*sc);
    v.z = pk2(x1.x*sc, x1.y*sc);
    v.w = pk2(x1.z*sc, x1.w*sc);
    *(uint4*)&sbf[(size_t)row*DIMM + lane*8] = v;
}

// ---------------------------------------------------------------------------
// K1b: lr/gate thin GEMM via MFMA: (32768 x 512) @ (512 x 16).
// ---------------------------------------------------------------------------
__global__ __launch_bounds__(256) void k_lr_gate(
    const uint16_t* __restrict__ sbf, const uint16_t* __restrict__ wsg,
    float* __restrict__ lr_t, float* __restrict__ gate_t)
{
    __shared__ uint16_t Asl[128][LDSP];
    int tid = threadIdx.x;
    int w = tid>>6, lane = tid&63, q = lane>>4, col = lane&15;
    int m0 = blockIdx.x*128;

    f32x4 acc[2];
    acc[0] = (f32x4){0.f,0.f,0.f,0.f};
    acc[1] = (f32x4){0.f,0.f,0.f,0.f};

    for (int k0=0;k0<DIMM;k0+=64){
        #pragma unroll
        for (int s=0;s<4;s++){
            int seg = s*256 + tid;
            int row = seg>>3, kk = seg&7;
            uint4 v = *(const uint4*)&sbf[(size_t)(m0+row)*DIMM + k0 + kk*8];
            *(uint4*)&Asl[row][kk*8] = v;
        }
        __syncthreads();
        #pragma unroll
        for (int ks=0;ks<64;ks+=32){
            short8 bf = *(const short8*)&wsg[(size_t)col*DIMM + k0 + ks + q*8];
            #pragma unroll
            for (int mt=0;mt<2;mt++){
                short8 af = *(const short8*)&Asl[w*32 + mt*16 + col][ks + q*8];
                acc[mt] = __builtin_amdgcn_mfma_f32_16x16x32_bf16(af, bf, acc[mt], 0,0,0);
            }
        }
        __syncthreads();
    }

    #pragma unroll
    for (int mt=0;mt<2;mt++){
        #pragma unroll
        for (int reg=0;reg<4;reg++){
            int m = m0 + w*32 + mt*16 + q*4 + reg;
            int b = m>>13, t = m&8191;
            float val = sigmoidf_(acc[mt][reg]);
            if (col < HH){
                lr_t[(size_t)m*HH + col] = val*MAX_LR;
            } else {
                int j = t-63;
                if (j >= 0)
                    gate_t[((size_t)b*TT + j)*HH + (col-HH)] = val;
            }
        }
    }
}

// ---------------------------------------------------------------------------
// K2: chunk means from sbf (bf16 seq*scale — halves traffic vs f32 seq).
// ---------------------------------------------------------------------------
__global__ __launch_bounds__(512) void k_chunk_gates(
    const uint16_t* __restrict__ sbf,
    const float* __restrict__ Wmom, const float* __restrict__ Wdecay,
    float* __restrict__ mom, float* __restrict__ dec)
{
    int blk = blockIdx.x;              // b*N + n
    int b = blk>>7, n = blk&127;
    int tid = threadIdx.x;
    size_t base = ((size_t)b*TT + n*CC)*DIMM + tid;
    float acc=0.f;
    #pragma unroll 8
    for (int j=0;j<CC;j++) acc += bf2f(sbf[base + (size_t)j*DIMM]);
    __shared__ float sm[DIMM];
    sm[tid] = acc*(1.0f/CC);
    __syncthreads();
    int wid = tid>>6, lane = tid&63;
    float d1=0.f, d2=0.f;
    #pragma unroll
    for (int i=0;i<8;i++){
        int idx=i*64+lane; float sv=sm[idx];
        d1 += sv*Wmom[idx*HH+wid];
        d2 += sv*Wdecay[idx*HH+wid];
    }
    #pragma unroll
    for (int o=32;o;o>>=1){ d1+=__shfl_down(d1,o,64); d2+=__shfl_down(d2,o,64); }
    if (lane==0){
        mom[(b*HH+wid)*NN + n] = sigmoidf_(d1);
        dec[(b*HH+wid)*NN + n] = sigmoidf_(d2);
    }
}

// ---------------------------------------------------------------------------
// K3: MFMA GEMM (R12 form). MODE 0/2: A+B via global_load_lds into linear
// [128][64] LDS, XOR swizzle group^=(row&7) on global source + reads.
// MODE 1: A f32*scale register-converted into padded [128][72].
// R15: MODE0 epilogue restages C through the freed shmem for dwordx4 stores.
// ---------------------------------------------------------------------------
template<int MODE>
__global__ __launch_bounds__(256) void k_gemm_mfma(
    const void* __restrict__ Av, const uint16_t* __restrict__ Bt,
    const float* __restrict__ scale, void* __restrict__ out0,
    void* __restrict__ out1)
{
    __shared__ __align__(16) uint16_t shmem[128*72 + 128*64];
    uint16_t* Asl = shmem;             // MODE1: padded 72; MODE0/2: linear 64
    uint16_t* Bsl = shmem + 128*72;    // linear 64, swizzled
    __shared__ float sscale[128];
    int tid = threadIdx.x;
    int wave = tid>>6, lane = tid&63;
    int q = lane>>4, col = lane&15;
    // bijective XCD swizzle: hw dispatch is x-fastest, XCD = bid%8.
    int bid = blockIdx.y*gridDim.x + blockIdx.x;
    int xcd = bid & 7, local = bid >> 3;
    int mper = gridDim.y >> 3;                  // m-tiles per XCD
    int m0 = (xcd*mper + local/gridDim.x)*128;
    int n0 = (local%gridDim.x)*128;
    int m_off = (wave&1)*64, n_off = (wave>>1)*64;

    if (MODE==1){
        if (tid<128) sscale[tid] = scale[m0+tid];
        __syncthreads();
    }

    f32x4 acc[4][4];
    #pragma unroll
    for (int i=0;i<4;i++)
        #pragma unroll
        for (int j=0;j<4;j++) acc[i][j] = (f32x4){0.f,0.f,0.f,0.f};

    int srow = wave*32 + (lane>>3);   // staging row (per lane), + s*8
    int sgs  = lane&7;                // staging group slot

    for (int k0=0;k0<DIMM;k0+=64){
        if (MODE!=1){
            const uint16_t* A = (const uint16_t*)Av;
            #pragma unroll
            for (int s=0;s<4;s++){
                int r = srow + s*8;
                gload_lds16(&A[(size_t)(m0+r)*DIMM + k0 + ((sgs ^ (r&7))<<3)],
                            &Asl[(wave*32 + s*8)*64]);
            }
        } else {
            const float* A = (const float*)Av;
            #pragma unroll
            for (int s=0;s<4;s++){
                int seg = s*256 + tid;
                int row = seg>>3, kk = seg&7;
                float sc = sscale[row];
                const float4* ap = (const float4*)&A[(size_t)(m0+row)*DIMM + k0 + kk*8];
                float4 a0 = ap[0], a1 = ap[1];
                uint4 v;
                v.x = pk2(a0.x*sc, a0.y*sc);
                v.y = pk2(a0.z*sc, a0.w*sc);
                v.z = pk2(a1.x*sc, a1.y*sc);
                v.w = pk2(a1.z*sc, a1.w*sc);
                *(uint4*)&Asl[row*72 + kk*8] = v;
            }
        }
        #pragma unroll
        for (int s=0;s<4;s++){
            int r = srow + s*8;
            gload_lds16(&Bt[(size_t)(n0+r)*DIMM + k0 + ((sgs ^ (r&7))<<3)],
                        &Bsl[(wave*32 + s*8)*64]);
        }
        __syncthreads();
        #pragma unroll
        for (int ks=0;ks<64;ks+=32){
            short8 af[4], bf[4];
            int g = q + (ks>>3);
            #pragma unroll
            for (int mt=0;mt<4;mt++){
                int r = m_off + mt*16 + col;
                if (MODE==1)
                    af[mt] = *(const short8*)&Asl[r*72 + ks + q*8];
                else
                    af[mt] = *(const short8*)&Asl[r*64 + ((g ^ (r&7))<<3)];
            }
            #pragma unroll
            for (int nt=0;nt<4;nt++){
                int rb = n_off + nt*16 + col;
                bf[nt] = *(const short8*)&Bsl[rb*64 + ((g ^ (rb&7))<<3)];
            }
            #pragma unroll
            for (int mt=0;mt<4;mt++)
                #pragma unroll
                for (int nt=0;nt<4;nt++)
                    acc[mt][nt] = __builtin_amdgcn_mfma_f32_16x16x32_bf16(
                        af[mt], bf[nt], acc[mt][nt], 0, 0, 0);
        }
        __syncthreads();
    }

    if (MODE==0){
        // restage C tile bf16 [128][128] in shmem (32KB <= 34.8KB free)
        #pragma unroll
        for (int mt=0;mt<4;mt++)
            #pragma unroll
            for (int reg=0;reg<4;reg++){
                int lrow = m_off + mt*16 + q*4 + reg;
                #pragma unroll
                for (int nt=0;nt<4;nt++){
                    int le = n_off + nt*16 + col;
                    shmem[lrow*128 + le] = f2bf(acc[mt][nt][reg]);
                }
            }
        __syncthreads();
        // coalesced dwordx4 stores: n0 is 128-aligned -> one buffer/block
        uint16_t* basep = (uint16_t*)((n0 < 512) ? out0 : out1);
        int h0 = (n0 & 511) >> 6;
        #pragma unroll
        for (int p=0;p<8;p++){
            int idx = p*256 + tid;          // 0..2047
            int lrow = idx >> 4, seg = idx & 15;
            int m = m0 + lrow;
            int b = m>>13, t = m&8191;
            int h = h0 + (seg>>3);
            int dk = (seg&7)*8;
            uint4 v = *(const uint4*)&shmem[lrow*128 + seg*8];
            *(uint4*)&basep[((size_t)(b*HH+h)*TT + t)*DD + dk] = v;
        }
    } else {
        #pragma unroll
        for (int mt=0;mt<4;mt++){
            #pragma unroll
            for (int reg=0;reg<4;reg++){
                int m = m0 + m_off + mt*16 + q*4 + reg;
                int b = m>>13, t = m&8191;
                if (MODE==1){
                    int j = t-63;
                    if (j>=0){
                        #pragma unroll
                        for (int nt=0;nt<4;nt++){
                            int e = n0 + n_off + nt*16 + col;
                            int h = e>>6, dk = e&63;
                            ((uint16_t*)out0)[((size_t)(b*HH+h)*TT + j)*DD + dk] = f2bf(acc[mt][nt][reg]);
                        }
                    }
                } else {
                    int tp = t + 63;
                    if (tp < TT){
                        #pragma unroll
                        for (int nt=0;nt<4;nt++){
                            int e = n0 + n_off + nt*16 + col;
                            ((float*)out0)[((size_t)b*TT + tp)*DIMM + e] = acc[mt][nt][reg];
                        }
                    }
                }
            }
        }
    }
}

// ---------------------------------------------------------------------------
// K4: per-chunk MLP gradient via MFMA. One block per (bh,n), 4 waves.
// R14 form: 5 LDS slots; weight A-operands direct from global.
// ---------------------------------------------------------------------------
__global__ __launch_bounds__(256) void k_grad(
    const uint16_t* __restrict__ kbuf, const uint16_t* __restrict__ vbuf,
    const float* __restrict__ lr_t, const uint16_t* __restrict__ w1t_bf,
    const uint16_t* __restrict__ w2t_bf, const uint16_t* __restrict__ w2b_bf,
    uint16_t* __restrict__ g1T, uint16_t* __restrict__ g2T)
{
    __shared__ uint16_t lds[5*64*LDSP];
    __shared__ float lr_sh[64];
    uint16_t* kcB  = lds + 0*64*LDSP;   // G1 B operand -> dxA after G2
    uint16_t* kcT  = lds + 1*64*LDSP;   // G5 B operand
    uint16_t* vB   = lds + 2*64*LDSP;   // G2 epilogue -> dxB (in-place)
    uint16_t* hA   = lds + 3*64*LDSP;   // G3 B operand
    uint16_t* hB   = lds + 4*64*LDSP;   // G2 B operand -> dx1T after G4
    uint16_t* dxA  = kcB;
    uint16_t* dxB  = vB;
    uint16_t* dx1T = hB;

    int bhn = blockIdx.x;
    int bh = bhn>>7, n = bhn&127;
    int b = bh>>3, h = bh&7;
    int tid = threadIdx.x, tx = tid&15, ty = tid>>4;
    int w = tid>>6, lane = tid&63, q = lane>>4, col = lane&15;
    size_t cbase = ((size_t)bh*TT + n*CC)*DD;

    // ---- stage kc (both layouts) + v ----
    #pragma unroll
    for (int r=0;r<4;r++){
        int row = ty*4+r;
        ushort4 k4 = *(const ushort4*)&kbuf[cbase + row*DD + tx*4];
        *(ushort4*)&kcB[row*LDSP + tx*4] = k4;
        kcT[(tx*4+0)*LDSP + row] = k4.x;
        kcT[(tx*4+1)*LDSP + row] = k4.y;
        kcT[(tx*4+2)*LDSP + row] = k4.z;
        kcT[(tx*4+3)*LDSP + row] = k4.w;
        ushort4 v4 = *(const ushort4*)&vbuf[cbase + row*DD + tx*4];
        *(ushort4*)&vB[row*LDSP + tx*4] = v4;
    }
    if (tid < 64) lr_sh[tid] = lr_t[((size_t)b*TT + n*CC + tid)*HH + h];
    __syncthreads();

    // ---- G1 (swapped): x1^T = (kc @ w1)^T. A = w1^T from GLOBAL ----
    f32x4 a1[4];
    #pragma unroll
    for (int i=0;i<4;i++) a1[i]=(f32x4){0.f,0.f,0.f,0.f};
    gemm64g(w1t_bf, kcB, w, q, col, a1);
    float sg[16], hr[16];
    #pragma unroll
    for (int nt=0;nt<4;nt++)
        #pragma unroll
        for (int reg=0;reg<4;reg++){
            int idx = nt*4+reg;
            float x = a1[nt][reg];
            float sgm = sigmoidf_(x);
            sg[idx]=sgm; hr[idx]=x*sgm;
            int d1 = w*16 + q*4 + reg;
            int token = nt*16 + col;
            uint16_t hv = f2bf(x*sgm);
            hA[d1*LDSP + token] = hv;      // natural
            hB[token*LDSP + d1] = hv;      // scatter
        }
    __syncthreads();

    // ---- G2 (swapped): x2^T = (h @ w2)^T; A = w2^T GLOBAL.
    //      dx2 = (2/D)*lr*(x2 - v); dxA -> kcB slot, dxB -> vB in-place ----
    f32x4 a2[4];
    #pragma unroll
    for (int i=0;i<4;i++) a2[i]=(f32x4){0.f,0.f,0.f,0.f};
    gemm64g(w2t_bf, hB, w, q, col, a2);
    __syncthreads();   // all kcB(G1)/hB(G2) reads done before slot reuse
    #pragma unroll
    for (int nt=0;nt<4;nt++)
        #pragma unroll
        for (int reg=0;reg<4;reg++){
            int d2 = w*16 + q*4 + reg;
            int token = nt*16 + col;
            float vv = bf2f(vB[token*LDSP + d2]);
            float dx = (2.0f/DD)*lr_sh[token]*(a2[nt][reg]-vv);
            uint16_t dv = f2bf(dx);
            dxA[d2*LDSP + token] = dv;     // kcB slot (dead)
            dxB[token*LDSP + d2] = dv;     // vB slot, same index as read
        }
    __syncthreads();

    // ---- G3: g2^T = dx2^T @ h  (rows=d2 strip, cols=d1) ----
    f32x4 a3[4];
    #pragma unroll
    for (int i=0;i<4;i++) a3[i]=(f32x4){0.f,0.f,0.f,0.f};
    gemm64(dxA, hA, w, q, col, a3);
    // ---- G4 (swapped): dh^T = w2 @ dx2^T; A = w2 GLOBAL ----
    f32x4 a4[4];
    #pragma unroll
    for (int i=0;i<4;i++) a4[i]=(f32x4){0.f,0.f,0.f,0.f};
    gemm64g(w2b_bf, dxB, w, q, col, a4);

    size_t gb = (size_t)bhn*4096;
    #pragma unroll
    for (int nt=0;nt<4;nt++)
        #pragma unroll
        for (int reg=0;reg<4;reg++){
            int d2 = w*16 + q*4 + reg;
            int d1 = nt*16 + col;
            g2T[gb + d2*DD + d1] = f2bf(-a3[nt][reg]);
        }
    #pragma unroll
    for (int nt=0;nt<4;nt++)
        #pragma unroll
        for (int reg=0;reg<4;reg++){
            int idx = nt*4+reg;
            int d1 = w*16 + q*4 + reg;
            int token = nt*16 + col;
            float dsl = sg[idx] + hr[idx]*(1.f-sg[idx]);
            dx1T[d1*LDSP + token] = f2bf(a4[nt][reg]*dsl);   // hB slot (dead)
        }
    __syncthreads();

    // ---- G5: g1^T = dx1^T @ kc  (rows=d1 strip, cols=p) ----
    f32x4 a5[4];
    #pragma unroll
    for (int i=0;i<4;i++) a5[i]=(f32x4){0.f,0.f,0.f,0.f};
    gemm64(dx1T, kcT, w, q, col, a5);
    #pragma unroll
    for (int nt=0;nt<4;nt++)
        #pragma unroll
        for (int reg=0;reg<4;reg++){
            int d1 = w*16 + q*4 + reg;
            int p  = nt*16 + col;
            g1T[gb + d1*DD + p] = f2bf(-a5[nt][reg]);
        }
}

// ---------------------------------------------------------------------------
// K5: scans. 8B/thread (4 recurrence lanes) + 4-deep load prefetch.
// ---------------------------------------------------------------------------
__global__ __launch_bounds__(256) void k_scan(
    uint16_t* __restrict__ g1, uint16_t* __restrict__ g2,
    const float* __restrict__ mom, const float* __restrict__ dec)
{
    int blk = blockIdx.x;            // [0,256)
    int arr = blk>>7; int rem = blk&127;
    int bh = rem>>2; int eg = rem&3;
    int e4 = eg*1024 + threadIdx.x*4;
    uint16_t* gp = arr ? g2 : g1;
    __shared__ float smg[NN], sdc[NN];
    if (threadIdx.x < NN){
        smg[threadIdx.x] = mom[bh*NN+threadIdx.x];
        sdc[threadIdx.x] = 1.f - dec[bh*NN+threadIdx.x];
    }
    __syncthreads();
    size_t base = (size_t)bh*NN*4096 + e4;
    float m0=0.f,m1=0.f,m2=0.f,m3=0.f, u0=0.f,u1=0.f,u2=0.f,u3=0.f;
    uint2 p0 = *(const uint2*)&gp[base];
    uint2 p1 = *(const uint2*)&gp[base + 4096];
    uint2 p2 = *(const uint2*)&gp[base + 2*4096];
    uint2 p3 = *(const uint2*)&gp[base + 3*4096];
    for (int t=0; t<NN; t+=4){
        uint2 c0=p0, c1=p1, c2=p2, c3=p3;
        if (t+4 < NN){                       // uniform branch
            p0 = *(const uint2*)&gp[base + (size_t)(t+4)*4096];
            p1 = *(const uint2*)&gp[base + (size_t)(t+5)*4096];
            p2 = *(const uint2*)&gp[base + (size_t)(t+6)*4096];
            p3 = *(const uint2*)&gp[base + (size_t)(t+7)*4096];
        }
        #pragma unroll
        for (int j=0;j<4;j++){
            uint2 c = (j==0)?c0:(j==1)?c1:(j==2)?c2:c3;
            float g = smg[t+j], d = sdc[t+j];
            float v0 = bf2f(c.x&0xffffu), v1 = bf2f(c.x>>16);
            float v2 = bf2f(c.y&0xffffu), v3 = bf2f(c.y>>16);
            m0 = fmaf(g,m0,v0); u0 = fmaf(d,u0,m0);
            m1 = fmaf(g,m1,v1); u1 = fmaf(d,u1,m1);
            m2 = fmaf(g,m2,v2); u2 = fmaf(d,u2,m2);
            m3 = fmaf(g,m3,v3); u3 = fmaf(d,u3,m3);
            uint2 r; r.x = pk2(u0,u1); r.y = pk2(u2,u3);
            *(uint2*)&gp[base + (size_t)(t+j)*4096] = r;
        }
    }
}

// ---------------------------------------------------------------------------
// K6: retrieve via MFMA. One block per (bh,n), 4 waves.
// ---------------------------------------------------------------------------
__global__ __launch_bounds__(256) void k_retrieve(
    const uint16_t* __restrict__ qbuf, const uint16_t* __restrict__ u1T,
    const uint16_t* __restrict__ u2T, const float* __restrict__ w1Tf,
    const float* __restrict__ w2Tf, const float* __restrict__ gamma,
    const float* __restrict__ gate_t, uint16_t* __restrict__ y)
{
    __shared__ uint16_t qc[64*LDSP];
    __shared__ uint16_t W1s[64*LDSP];   // (w1+u1)^T rows: [d1][p]
    __shared__ uint16_t W2s[64*LDSP];   // (w2+u2)^T rows: [d2][d1]
    __shared__ uint16_t hB[64*LDSP];    // h rows: [token][d1]
    __shared__ float gate_sh[64], gam_sh[64];
    int bhn = blockIdx.x;
    int bh = bhn>>7, n = bhn&127;
    int b = bh>>3, h = bh&7;
    int tid = threadIdx.x, tx = tid&15, ty = tid>>4;
    int w = tid>>6, lane = tid&63, q = lane>>4, col = lane&15;
    size_t cbase = ((size_t)bh*TT + n*CC)*DD;
    size_t ub = (size_t)bhn*4096;

    #pragma unroll
    for (int r=0;r<4;r++){
        int row = ty*4+r;     // d_out index for W staging; token for qc
        *(ushort4*)&qc[row*LDSP + tx*4] =
            *(const ushort4*)&qbuf[cbase + row*DD + tx*4];
        ushort4 u14 = *(const ushort4*)&u1T[ub + row*DD + tx*4];
        float4 w1v = *(const float4*)&w1Tf[row*DD + tx*4];
        ushort4 s1;
        s1.x = f2bf(w1v.x + bf2f(u14.x));
        s1.y = f2bf(w1v.y + bf2f(u14.y));
        s1.z = f2bf(w1v.z + bf2f(u14.z));
        s1.w = f2bf(w1v.w + bf2f(u14.w));
        *(ushort4*)&W1s[row*LDSP + tx*4] = s1;
        ushort4 u24 = *(const ushort4*)&u2T[ub + row*DD + tx*4];
        float4 w2v = *(const float4*)&w2Tf[row*DD + tx*4];
        ushort4 s2;
        s2.x = f2bf(w2v.x + bf2f(u24.x));
        s2.y = f2bf(w2v.y + bf2f(u24.y));
        s2.z = f2bf(w2v.z + bf2f(u24.z));
        s2.w = f2bf(w2v.w + bf2f(u24.w));
        *(ushort4*)&W2s[row*LDSP + tx*4] = s2;
    }
    if (tid < 64){
        gate_sh[tid] = gate_t[((size_t)b*TT + n*CC + tid)*HH + h];
        gam_sh[tid]  = gamma[h*DD + tid];
    }
    __syncthreads();

    // G1: x1 = qc @ (w1+u1); h = silu
    f32x4 a1[4];
    #pragma unroll
    for (int i=0;i<4;i++) a1[i]=(f32x4){0.f,0.f,0.f,0.f};
    gemm64(qc, W1s, w, q, col, a1);
    #pragma unroll
    for (int nt=0;nt<4;nt++)
        #pragma unroll
        for (int reg=0;reg<4;reg++){
            float x = a1[nt][reg];
            int token = w*16 + q*4 + reg;
            int d1 = nt*16 + col;
            hB[token*LDSP + d1] = f2bf(x*sigmoidf_(x));
        }
    __syncthreads();

    // G2: x = h @ (w2+u2); rmsnorm(d=64) * (1+gamma) * gate -> y
    f32x4 a2[4];
    #pragma unroll
    for (int i=0;i<4;i++) a2[i]=(f32x4){0.f,0.f,0.f,0.f};
    gemm64(hB, W2s, w, q, col, a2);
    #pragma unroll
    for (int reg=0;reg<4;reg++){
        float p = 0.f;
        #pragma unroll
        for (int nt=0;nt<4;nt++) p += a2[nt][reg]*a2[nt][reg];
        p += __shfl_xor(p,1,64);
        p += __shfl_xor(p,2,64);
        p += __shfl_xor(p,4,64);
        p += __shfl_xor(p,8,64);
        float sclv = rsqrtf(p*(1.0f/DD)+EPS);
        int token = w*16 + q*4 + reg;
        float gt = gate_sh[token];
        size_t yb = ((size_t)b*TT + n*CC + token)*DIMM + h*DD;
        #pragma unroll
        for (int nt=0;nt<4;nt++){
            int d2 = nt*16 + col;
            y[yb + d2] = f2bf(a2[nt][reg]*sclv*(1.f+gam_sh[d2])*gt);
        }
    }
}

// ---------------------------------------------------------------------------
// K7: zero pads (unchanged)
// ---------------------------------------------------------------------------
__global__ __launch_bounds__(256) void k_zero(
    uint16_t* __restrict__ qbuf, float* __restrict__ out, float* __restrict__ gate_t)
{
    int g = blockIdx.x*256 + threadIdx.x;
    const int QN = BHH*63*DD;          // 129024
    const int ON = BB*63*DIMM;         // 129024
    const int GN = BB*63*HH;           // 2016
    if (g < QN){
        int bh = g/4032; int r = g - bh*4032;
        int j = 8129 + (r>>6); int dk = r&63;
        qbuf[((size_t)bh*TT + j)*DD + dk] = 0;
    } else if (g < QN+ON){
        int g2i = g - QN;
        int b = g2i/(63*512); int r = g2i - b*63*512;
        int t = r>>9; int e = r&511;
        out[((size_t)b*TT + t)*DIMM + e] = 0.f;
    } else if (g < QN+ON+GN){
        int g3 = g - QN - ON;
        int b = g3/(63*HH); int r = g3 - b*63*HH;
        int j = 8129 + (r>>3); int hh = r&7;
        gate_t[((size_t)b*TT + j)*HH + hh] = 0.f;
    }
}

// ---------------------------------------------------------------------------
extern "C" void kernel_launch(void* const* d_in, const int* in_sizes, int n_in,
                              void* d_out, int out_size, void* d_ws, size_t ws_size,
                              hipStream_t stream)
{
    (void)in_sizes; (void)n_in; (void)out_size; (void)ws_size;
    const float* seq    = (const float*)d_in[0];
    const float* w1     = (const float*)d_in[1];
    const float* w2     = (const float*)d_in[2];
    const float* Wq     = (const float*)d_in[3];
    const float* Wkv    = (const float*)d_in[4];
    const float* Wstep  = (const float*)d_in[5];
    const float* Wmom   = (const float*)d_in[6];
    const float* Wdecay = (const float*)d_in[7];
    const float* Wgate  = (const float*)d_in[8];
    const float* Wcomb  = (const float*)d_in[9];
    const float* gamma  = (const float*)d_in[10];
    float* out = (float*)d_out;

    float* scale = (float*)d_ws;          // 32768
    float* lr_t  = scale + 32768;         // 262144  [b][t][h]
    float* gate_t= lr_t + 262144;         // 262144  [b][j][h]
    float* mom   = gate_t + 262144;       // 4096
    float* dec   = mom + 4096;            // 4096
    float* w1t_f = dec + 4096;            // 4096 f32 w1^T
    float* w2t_f = w1t_f + 4096;          // 4096 f32 w2^T
    uint16_t* w1t_bf = (uint16_t*)(w2t_f + 4096);  // [64][64] bf16 w1^T
    uint16_t* w2t_bf = w1t_bf + 4096;              // [64][64] bf16 w2^T
    uint16_t* w2b_bf = w2t_bf + 4096;              // [64][64] bf16 w2
    uint16_t* btkv = w2b_bf + 4096;          // 1024*512 bf16 [n][k]
    uint16_t* btq  = btkv + 1024*512;        // 512*512
    uint16_t* btc  = btq  + 512*512;         // 512*512
    uint16_t* kb = btc + 512*512;            // 16777216 bf16 (q reuses after k_grad)
    uint16_t* vb = kb + 16777216;            // 16777216 bf16 (y reuses after k_retrieve)
    uint16_t* g1 = vb + 16777216;            // 16777216 bf16 g1^T (scan -> upd1^T)
    uint16_t* g2 = g1 + 16777216;            // 16777216 bf16 g2^T (scan -> upd2^T)
    uint16_t* sbf = g1;                      // [32768][512] bf16 seq*scale —
                                             // aliases g1 (dead until k_grad)
    uint16_t* wsg = g2;                      // [16][512] bf16 [Wstep|Wgate]^T —
                                             // aliases g2 (dead until k_grad)

    k_prep <<<1057, 256, 0, stream>>>(Wkv, Wq, Wcomb, Wstep, Wgate, w1, w2,
                                      btkv, btq, btc, wsg,
                                      w1t_bf, w2t_bf, w2b_bf, w1t_f, w2t_f);
    k_scale     <<<8192, 256, 0, stream>>>(seq, scale, sbf);
    k_lr_gate   <<<256, 256, 0, stream>>>(sbf, wsg, lr_t, gate_t);
    k_chunk_gates<<<BB*NN, 512, 0, stream>>>(sbf, Wmom, Wdecay, mom, dec);
    k_gemm_mfma<0><<<dim3(8, 256), 256, 0, stream>>>(sbf, btkv, nullptr, kb, vb);
    k_grad   <<<BHH*NN, 256, 0, stream>>>(kb, vb, lr_t, w1t_bf, w2t_bf, w2b_bf, g1, g2);
    k_scan   <<<256, 256, 0, stream>>>(g1, g2, mom, dec);
    k_gemm_mfma<1><<<dim3(4, 256), 256, 0, stream>>>(seq, btq, scale, kb /*q*/, nullptr);
    k_zero   <<<1017, 256, 0, stream>>>(kb /*q*/, out, gate_t);
    k_retrieve<<<BHH*NN, 256, 0, stream>>>(kb /*q*/, g1, g2, w1t_f, w2t_f, gamma, gate_t, vb /*y*/);
    k_gemm_mfma<2><<<dim3(4, 256), 256, 0, stream>>>(vb /*y*/, btc, nullptr, out, nullptr);
}

// Round 12
// 342.935 us; speedup vs baseline: 1.1052x; 1.0431x over previous
//
#include <hip/hip_runtime.h>
#include <cstdint>

// NeuralMemory forward. MFMA bf16 for big GEMMs + per-chunk MLP grad/retrieve.
// Shapes (fixed): B=4 T=8192 DIM=512 H=8 D=64 C=64 N=128 BH=32
// R5..R15: see history (559 -> 357.7us).
// R16: k_grad conflict fix via R12 toolkit: kcB/vB = swizzled linear-64
//     tiles staged by global_load_lds (pre-swizzled source); kcT built by
//     conflict-free in-LDS transpose (was the 8-way u16 scatter = 8.1M
//     conflict cycles); dxA/dxB reuse swizzled slots. gemm64u<AM,BM>
//     template: operand from padded-72 LDS / swizzled-64 LDS / global.
//     Merged k_lr_gate+k_chunk_gates -> k_post_sbf; k_scan+k_zero ->
//     k_scan_zero (11 -> 9 launches).
#define EPS     1.1920929e-07f
#define MAX_LR  0.01f
#define BB      4
#define TT      8192
#define DIMM    512
#define HH      8
#define DD      64
#define CC      64
#define NN      128
#define BHH     32
#define LDSP    72      // LDS row stride (bf16) for padded layouts

typedef __attribute__((ext_vector_type(8))) short short8;
typedef __attribute__((ext_vector_type(4))) float f32x4;

__device__ __forceinline__ float sigmoidf_(float x){ return 1.0f/(1.0f+__expf(-x)); }
__device__ __forceinline__ float bf2f(uint32_t lo16){ return __uint_as_float(lo16<<16); }
__device__ __forceinline__ uint16_t f2bf(float f){
    uint32_t x = __float_as_uint(f);
    return (uint16_t)((x + 0x7fffu + ((x>>16)&1u)) >> 16);   // RNE
}
__device__ __forceinline__ uint32_t pk2(float a, float b){
    return (uint32_t)f2bf(a) | ((uint32_t)f2bf(b)<<16);
}
// async global->LDS, 16B/lane. LDS dest = wave-uniform base + lane*16.
__device__ __forceinline__ void gload_lds16(const uint16_t* g, uint16_t* l){
    __builtin_amdgcn_global_load_lds(
        (const __attribute__((address_space(1))) unsigned int*)g,
        (__attribute__((address_space(3))) unsigned int*)l, 16, 0, 0);
}

// 64x64x64 GEMM slice. Operand modes: 0 = padded-72 LDS row [r][k],
// 1 = swizzled linear-64 LDS (group g at slot g^(r&7)), 2 = global [64][64].
template<int AM, int BM>
__device__ __forceinline__ void gemm64u(const uint16_t* A, const uint16_t* B,
                                        int strip, int q, int col, f32x4* acc)
{
    #pragma unroll
    for (int ks=0; ks<64; ks+=32){
        int g = q + (ks>>3);
        int ra = strip*16+col;
        short8 af;
        if (AM==0)      af = *(const short8*)&A[ra*LDSP + ks + q*8];
        else if (AM==1) af = *(const short8*)&A[ra*64 + ((g ^ (ra&7))<<3)];
        else            af = *(const short8*)&A[ra*DD + ks + q*8];
        #pragma unroll
        for (int nt=0;nt<4;nt++){
            int rb = nt*16+col;
            short8 bf;
            if (BM==0) bf = *(const short8*)&B[rb*LDSP + ks + q*8];
            else       bf = *(const short8*)&B[rb*64 + ((g ^ (rb&7))<<3)];
            acc[nt] = __builtin_amdgcn_mfma_f32_16x16x32_bf16(af, bf, acc[nt], 0,0,0);
        }
    }
}

// ---------------------------------------------------------------------------
// K0: merged prep. blk<512: Wkv->btkv; <768: Wq->btq; <1024: Wcomb->btc;
// <1056: pack [Wstep|Wgate]->wsg; ==1056: pack w1^T/w2^T/w2.
// ---------------------------------------------------------------------------
__global__ __launch_bounds__(256) void k_prep(
    const float* __restrict__ Wkv, const float* __restrict__ Wq,
    const float* __restrict__ Wcomb, const float* __restrict__ Wstep,
    const float* __restrict__ Wgate, const float* __restrict__ w1,
    const float* __restrict__ w2,
    uint16_t* __restrict__ btkv, uint16_t* __restrict__ btq,
    uint16_t* __restrict__ btc, uint16_t* __restrict__ wsg,
    uint16_t* __restrict__ w1t_bf, uint16_t* __restrict__ w2t_bf,
    uint16_t* __restrict__ w2b_bf, float* __restrict__ w1t_f,
    float* __restrict__ w2t_f)
{
    __shared__ float tile[32][33];
    __shared__ float t1[64][65];
    __shared__ float t2[64][65];
    int blk = blockIdx.x;
    if (blk < 1024){
        const float* in; uint16_t* out; int Ncols; int i;
        if (blk < 512){ in=Wkv; out=btkv; Ncols=1024; i=blk; }
        else if (blk < 768){ in=Wq; out=btq; Ncols=512; i=blk-512; }
        else { in=Wcomb; out=btc; Ncols=512; i=blk-768; }
        int nx = Ncols>>5;
        int bx = (i % nx)*32, by = (i / nx)*32;
        int lx = threadIdx.x&31, ly = threadIdx.x>>5;   // 32 x 8
        #pragma unroll
        for (int r=0;r<4;r++)
            tile[ly+8*r][lx] = in[(size_t)(by+ly+8*r)*Ncols + bx+lx];
        __syncthreads();
        #pragma unroll
        for (int r=0;r<4;r++)
            out[(size_t)(bx+ly+8*r)*DIMM + by+lx] = f2bf(tile[lx][ly+8*r]);
    } else if (blk < 1056){
        int g = (blk-1024)*256 + threadIdx.x;   // 8192 total
        int j = g >> 9, k = g & 511;
        float v = (j < HH) ? Wstep[k*HH + j] : Wgate[k*HH + (j-HH)];
        wsg[j*DIMM + k] = f2bf(v);
    } else {
        int tx = threadIdx.x & 63, ty = threadIdx.x >> 6;   // 64 x 4
        #pragma unroll
        for (int i=0;i<16;i++){
            int row = ty*16 + i;
            float v1 = w1[row*DD + tx];
            float v2 = w2[row*DD + tx];
            t1[row][tx] = v1;
            t2[row][tx] = v2;
            w2b_bf[row*DD + tx] = f2bf(v2);
        }
        __syncthreads();
        #pragma unroll
        for (int i=0;i<16;i++){
            int row = ty*16 + i;
            float v1 = t1[tx][row];     // w1[p=tx][d1=row] -> w1t[row][tx]
            float v2 = t2[tx][row];
            w1t_f[row*DD + tx] = v1;
            w1t_bf[row*DD + tx] = f2bf(v1);
            w2t_f[row*DD + tx] = v2;
            w2t_bf[row*DD + tx] = f2bf(v2);
        }
    }
}

// ---------------------------------------------------------------------------
// K1a: wave-per-row rmsnorm scale + bf16(seq*scale) stream-out.
// ---------------------------------------------------------------------------
__global__ __launch_bounds__(256) void k_scale(
    const float* __restrict__ seq, float* __restrict__ scale,
    uint16_t* __restrict__ sbf)
{
    int wave = threadIdx.x >> 6, lane = threadIdx.x & 63;
    int row = blockIdx.x*4 + wave;          // b*T + t
    const float4* sp = (const float4*)&seq[(size_t)row*DIMM + lane*8];
    float4 x0 = sp[0], x1 = sp[1];
    float ss = x0.x*x0.x + x0.y*x0.y + x0.z*x0.z + x0.w*x0.w
             + x1.x*x1.x + x1.y*x1.y + x1.z*x1.z + x1.w*x1.w;
    #pragma unroll
    for (int o=32;o;o>>=1) ss += __shfl_xor(ss,o,64);
    float sc = rsqrtf(ss*(1.0f/DIMM)+EPS);
    if (lane==0) scale[row] = sc;
    uint4 v;
    v.x = pk2(x0.x*sc, x0.y*sc);
    v.y = pk2(x0.z*sc, x0.w*sc);
    v.z = pk2(x1.x*sc, x1.y*sc);
    v.w = pk2(x1.z*sc, x1.w*sc);
    *(uint4*)&sbf[(size_t)row*DIMM + lane*8] = v;
}

// ---------------------------------------------------------------------------
// K1b: merged lr/gate thin GEMM (blk<256) + chunk gates (blk 256..767).
// Both depend only on sbf; independent of each other.
// ---------------------------------------------------------------------------
__global__ __launch_bounds__(256) void k_post_sbf(
    const uint16_t* __restrict__ sbf, const uint16_t* __restrict__ wsg,
    const float* __restrict__ Wmom, const float* __restrict__ Wdecay,
    float* __restrict__ lr_t, float* __restrict__ gate_t,
    float* __restrict__ mom, float* __restrict__ dec)
{
    __shared__ uint16_t Asl[128][LDSP];
    __shared__ float sm[DIMM];
    int blk = blockIdx.x;
    int tid = threadIdx.x;
    if (blk < 256){
        int w = tid>>6, lane = tid&63, q = lane>>4, col = lane&15;
        int m0 = blk*128;
        f32x4 acc[2];
        acc[0] = (f32x4){0.f,0.f,0.f,0.f};
        acc[1] = (f32x4){0.f,0.f,0.f,0.f};
        for (int k0=0;k0<DIMM;k0+=64){
            #pragma unroll
            for (int s=0;s<4;s++){
                int seg = s*256 + tid;
                int row = seg>>3, kk = seg&7;
                uint4 v = *(const uint4*)&sbf[(size_t)(m0+row)*DIMM + k0 + kk*8];
                *(uint4*)&Asl[row][kk*8] = v;
            }
            __syncthreads();
            #pragma unroll
            for (int ks=0;ks<64;ks+=32){
                short8 bf = *(const short8*)&wsg[(size_t)col*DIMM + k0 + ks + q*8];
                #pragma unroll
                for (int mt=0;mt<2;mt++){
                    short8 af = *(const short8*)&Asl[w*32 + mt*16 + col][ks + q*8];
                    acc[mt] = __builtin_amdgcn_mfma_f32_16x16x32_bf16(af, bf, acc[mt], 0,0,0);
                }
            }
            __syncthreads();
        }
        #pragma unroll
        for (int mt=0;mt<2;mt++){
            #pragma unroll
            for (int reg=0;reg<4;reg++){
                int m = m0 + w*32 + mt*16 + q*4 + reg;
                int b = m>>13, t = m&8191;
                float val = sigmoidf_(acc[mt][reg]);
                if (col < HH){
                    lr_t[(size_t)m*HH + col] = val*MAX_LR;
                } else {
                    int j = t-63;
                    if (j >= 0)
                        gate_t[((size_t)b*TT + j)*HH + (col-HH)] = val;
                }
            }
        }
    } else {
        int cblk = blk - 256;              // b*N + n
        int b = cblk>>7, n = cblk&127;
        size_t base = ((size_t)b*TT + n*CC)*DIMM + tid;
        float a0=0.f, a1=0.f;
        #pragma unroll 8
        for (int j=0;j<CC;j++){
            a0 += bf2f(sbf[base + (size_t)j*DIMM]);
            a1 += bf2f(sbf[base + 256 + (size_t)j*DIMM]);
        }
        sm[tid] = a0*(1.0f/CC);
        sm[tid+256] = a1*(1.0f/CC);
        __syncthreads();
        int wid = tid>>6, lane = tid&63;   // 4 waves, each h=wid and h=wid+4
        float d1a=0.f, d1b=0.f, d2a=0.f, d2b=0.f;
        #pragma unroll
        for (int i=0;i<8;i++){
            int idx=i*64+lane; float sv=sm[idx];
            d1a += sv*Wmom[idx*HH+wid];
            d1b += sv*Wmom[idx*HH+wid+4];
            d2a += sv*Wdecay[idx*HH+wid];
            d2b += sv*Wdecay[idx*HH+wid+4];
        }
        #pragma unroll
        for (int o=32;o;o>>=1){
            d1a+=__shfl_down(d1a,o,64); d1b+=__shfl_down(d1b,o,64);
            d2a+=__shfl_down(d2a,o,64); d2b+=__shfl_down(d2b,o,64);
        }
        if (lane==0){
            mom[(b*HH+wid)*NN + n]   = sigmoidf_(d1a);
            mom[(b*HH+wid+4)*NN + n] = sigmoidf_(d1b);
            dec[(b*HH+wid)*NN + n]   = sigmoidf_(d2a);
            dec[(b*HH+wid+4)*NN + n] = sigmoidf_(d2b);
        }
    }
}

// ---------------------------------------------------------------------------
// K3: MFMA GEMM (R12 form). MODE 0/2: A+B via global_load_lds into linear
// [128][64] LDS, XOR swizzle group^=(row&7) on global source + reads.
// MODE 1: A f32*scale register-converted into padded [128][72].
// MODE0 epilogue restages C through the freed shmem for dwordx4 stores.
// ---------------------------------------------------------------------------
template<int MODE>
__global__ __launch_bounds__(256) void k_gemm_mfma(
    const void* __restrict__ Av, const uint16_t* __restrict__ Bt,
    const float* __restrict__ scale, void* __restrict__ out0,
    void* __restrict__ out1)
{
    __shared__ __align__(16) uint16_t shmem[128*72 + 128*64];
    uint16_t* Asl = shmem;             // MODE1: padded 72; MODE0/2: linear 64
    uint16_t* Bsl = shmem + 128*72;    // linear 64, swizzled
    __shared__ float sscale[128];
    int tid = threadIdx.x;
    int wave = tid>>6, lane = tid&63;
    int q = lane>>4, col = lane&15;
    // bijective XCD swizzle: hw dispatch is x-fastest, XCD = bid%8.
    int bid = blockIdx.y*gridDim.x + blockIdx.x;
    int xcd = bid & 7, local = bid >> 3;
    int mper = gridDim.y >> 3;                  // m-tiles per XCD
    int m0 = (xcd*mper + local/gridDim.x)*128;
    int n0 = (local%gridDim.x)*128;
    int m_off = (wave&1)*64, n_off = (wave>>1)*64;

    if (MODE==1){
        if (tid<128) sscale[tid] = scale[m0+tid];
        __syncthreads();
    }

    f32x4 acc[4][4];
    #pragma unroll
    for (int i=0;i<4;i++)
        #pragma unroll
        for (int j=0;j<4;j++) acc[i][j] = (f32x4){0.f,0.f,0.f,0.f};

    int srow = wave*32 + (lane>>3);   // staging row (per lane), + s*8
    int sgs  = lane&7;                // staging group slot

    for (int k0=0;k0<DIMM;k0+=64){
        if (MODE!=1){
            const uint16_t* A = (const uint16_t*)Av;
            #pragma unroll
            for (int s=0;s<4;s++){
                int r = srow + s*8;
                gload_lds16(&A[(size_t)(m0+r)*DIMM + k0 + ((sgs ^ (r&7))<<3)],
                            &Asl[(wave*32 + s*8)*64]);
            }
        } else {
            const float* A = (const float*)Av;
            #pragma unroll
            for (int s=0;s<4;s++){
                int seg = s*256 + tid;
                int row = seg>>3, kk = seg&7;
                float sc = sscale[row];
                const float4* ap = (const float4*)&A[(size_t)(m0+row)*DIMM + k0 + kk*8];
                float4 a0 = ap[0], a1 = ap[1];
                uint4 v;
                v.x = pk2(a0.x*sc, a0.y*sc);
                v.y = pk2(a0.z*sc, a0.w*sc);
                v.z = pk2(a1.x*sc, a1.y*sc);
                v.w = pk2(a1.z*sc, a1.w*sc);
                *(uint4*)&Asl[row*72 + kk*8] = v;
            }
        }
        #pragma unroll
        for (int s=0;s<4;s++){
            int r = srow + s*8;
            gload_lds16(&Bt[(size_t)(n0+r)*DIMM + k0 + ((sgs ^ (r&7))<<3)],
                        &Bsl[(wave*32 + s*8)*64]);
        }
        __syncthreads();
        #pragma unroll
        for (int ks=0;ks<64;ks+=32){
            short8 af[4], bf[4];
            int g = q + (ks>>3);
            #pragma unroll
            for (int mt=0;mt<4;mt++){
                int r = m_off + mt*16 + col;
                if (MODE==1)
                    af[mt] = *(const short8*)&Asl[r*72 + ks + q*8];
                else
                    af[mt] = *(const short8*)&Asl[r*64 + ((g ^ (r&7))<<3)];
            }
            #pragma unroll
            for (int nt=0;nt<4;nt++){
                int rb = n_off + nt*16 + col;
                bf[nt] = *(const short8*)&Bsl[rb*64 + ((g ^ (rb&7))<<3)];
            }
            #pragma unroll
            for (int mt=0;mt<4;mt++)
                #pragma unroll
                for (int nt=0;nt<4;nt++)
                    acc[mt][nt] = __builtin_amdgcn_mfma_f32_16x16x32_bf16(
                        af[mt], bf[nt], acc[mt][nt], 0, 0, 0);
        }
        __syncthreads();
    }

    if (MODE==0){
        // restage C tile bf16 [128][128] in shmem (32KB <= 34.8KB free)
        #pragma unroll
        for (int mt=0;mt<4;mt++)
            #pragma unroll
            for (int reg=0;reg<4;reg++){
                int lrow = m_off + mt*16 + q*4 + reg;
                #pragma unroll
                for (int nt=0;nt<4;nt++){
                    int le = n_off + nt*16 + col;
                    shmem[lrow*128 + le] = f2bf(acc[mt][nt][reg]);
                }
            }
        __syncthreads();
        // coalesced dwordx4 stores: n0 is 128-aligned -> one buffer/block
        uint16_t* basep = (uint16_t*)((n0 < 512) ? out0 : out1);
        int h0 = (n0 & 511) >> 6;
        #pragma unroll
        for (int p=0;p<8;p++){
            int idx = p*256 + tid;          // 0..2047
            int lrow = idx >> 4, seg = idx & 15;
            int m = m0 + lrow;
            int b = m>>13, t = m&8191;
            int h = h0 + (seg>>3);
            int dk = (seg&7)*8;
            uint4 v = *(const uint4*)&shmem[lrow*128 + seg*8];
            *(uint4*)&basep[((size_t)(b*HH+h)*TT + t)*DD + dk] = v;
        }
    } else {
        #pragma unroll
        for (int mt=0;mt<4;mt++){
            #pragma unroll
            for (int reg=0;reg<4;reg++){
                int m = m0 + m_off + mt*16 + q*4 + reg;
                int b = m>>13, t = m&8191;
                if (MODE==1){
                    int j = t-63;
                    if (j>=0){
                        #pragma unroll
                        for (int nt=0;nt<4;nt++){
                            int e = n0 + n_off + nt*16 + col;
                            int h = e>>6, dk = e&63;
                            ((uint16_t*)out0)[((size_t)(b*HH+h)*TT + j)*DD + dk] = f2bf(acc[mt][nt][reg]);
                        }
                    }
                } else {
                    int tp = t + 63;
                    if (tp < TT){
                        #pragma unroll
                        for (int nt=0;nt<4;nt++){
                            int e = n0 + n_off + nt*16 + col;
                            ((float*)out0)[((size_t)b*TT + tp)*DIMM + e] = acc[mt][nt][reg];
                        }
                    }
                }
            }
        }
    }
}

// ---------------------------------------------------------------------------
// K4: per-chunk MLP gradient via MFMA. One block per (bh,n), 4 waves.
// R16: kcB/vB = swizzled linear-64 via global_load_lds; kcT via in-LDS
// transpose; dxA<-kcB, dxB<-vB (same swizzled addr as read), dx1T<-hB.
// Weight A-operands direct from global. Outputs -g1^T, -g2^T bf16.
// ---------------------------------------------------------------------------
__global__ __launch_bounds__(256) void k_grad(
    const uint16_t* __restrict__ kbuf, const uint16_t* __restrict__ vbuf,
    const float* __restrict__ lr_t, const uint16_t* __restrict__ w1t_bf,
    const uint16_t* __restrict__ w2t_bf, const uint16_t* __restrict__ w2b_bf,
    uint16_t* __restrict__ g1T, uint16_t* __restrict__ g2T)
{
    __shared__ __align__(16) uint16_t kcB[64*64];  // swz -> dxA after G2
    __shared__ __align__(16) uint16_t kcT[64*64];  // swz (kc^T)
    __shared__ __align__(16) uint16_t vB [64*64];  // swz -> dxB (in-place)
    __shared__ uint16_t hA[64*LDSP];               // [d1][token] padded
    __shared__ uint16_t hB[64*LDSP];               // [token][d1] -> dx1T
    __shared__ float lr_sh[64];
    uint16_t* dxA  = kcB;
    uint16_t* dxB  = vB;
    uint16_t* dx1T = hB;

    int bhn = blockIdx.x;
    int bh = bhn>>7, n = bhn&127;
    int b = bh>>3, h = bh&7;
    int tid = threadIdx.x;
    int w = tid>>6, lane = tid&63, q = lane>>4, col = lane&15;
    size_t cbase = ((size_t)bh*TT + n*CC)*DD;

    // ---- stage kcB, vB via global_load_lds (swizzled source) ----
    int srow8 = lane>>3, sgs = lane&7;
    #pragma unroll
    for (int s=0;s<2;s++){
        int r = w*16 + s*8 + srow8;
        gload_lds16(&kbuf[cbase + (size_t)r*DD + ((sgs ^ (r&7))<<3)],
                    &kcB[(w*16 + s*8)*64]);
        gload_lds16(&vbuf[cbase + (size_t)r*DD + ((sgs ^ (r&7))<<3)],
                    &vB[(w*16 + s*8)*64]);
    }
    if (tid < 64) lr_sh[tid] = lr_t[((size_t)b*TT + n*CC + tid)*HH + h];
    __syncthreads();

    // ---- kcT = kc^T (conflict-free in-LDS transpose, both sides swz) ----
    #pragma unroll
    for (int it=0; it<2; it++){
        int task = tid + it*256;       // 0..511
        int p = task & 63, g = task >> 6;   // g in 0..7 (token group)
        ushort4 lo, hi;
        uint16_t* dst;
        {
            int pg = p>>3, pw = p&7;
            lo.x = kcB[(g*8+0)*64 + ((pg ^ 0)<<3) + pw];
            lo.y = kcB[(g*8+1)*64 + ((pg ^ 1)<<3) + pw];
            lo.z = kcB[(g*8+2)*64 + ((pg ^ 2)<<3) + pw];
            lo.w = kcB[(g*8+3)*64 + ((pg ^ 3)<<3) + pw];
            hi.x = kcB[(g*8+4)*64 + ((pg ^ 4)<<3) + pw];
            hi.y = kcB[(g*8+5)*64 + ((pg ^ 5)<<3) + pw];
            hi.z = kcB[(g*8+6)*64 + ((pg ^ 6)<<3) + pw];
            hi.w = kcB[(g*8+7)*64 + ((pg ^ 7)<<3) + pw];
            dst = &kcT[p*64 + ((g ^ (p&7))<<3)];
        }
        *(ushort4*)dst = lo;
        *(ushort4*)(dst+4) = hi;
    }

    // ---- G1 (swapped): x1^T = (kc @ w1)^T. A = w1^T GLOBAL, B = kcB swz ----
    f32x4 a1[4];
    #pragma unroll
    for (int i=0;i<4;i++) a1[i]=(f32x4){0.f,0.f,0.f,0.f};
    gemm64u<2,1>(w1t_bf, kcB, w, q, col, a1);
    float sg[16], hr[16];
    #pragma unroll
    for (int nt=0;nt<4;nt++)
        #pragma unroll
        for (int reg=0;reg<4;reg++){
            int idx = nt*4+reg;
            float x = a1[nt][reg];
            float sgm = sigmoidf_(x);
            sg[idx]=sgm; hr[idx]=x*sgm;
            int d1 = w*16 + q*4 + reg;
            int token = nt*16 + col;
            uint16_t hv = f2bf(x*sgm);
            hA[d1*LDSP + token] = hv;
            hB[token*LDSP + d1] = hv;
        }
    __syncthreads();

    // ---- G2 (swapped): x2^T = (h @ w2)^T; A = w2^T GLOBAL, B = hB ----
    f32x4 a2[4];
    #pragma unroll
    for (int i=0;i<4;i++) a2[i]=(f32x4){0.f,0.f,0.f,0.f};
    gemm64u<2,0>(w2t_bf, hB, w, q, col, a2);
    __syncthreads();   // kcB(G1+transpose)/hB(G2) reads done before reuse
    #pragma unroll
    for (int nt=0;nt<4;nt++)
        #pragma unroll
        for (int reg=0;reg<4;reg++){
            int d2 = w*16 + q*4 + reg;
            int token = nt*16 + col;
            int vaddr = token*64 + (((d2>>3) ^ (token&7))<<3) + (d2&7);
            float vv = bf2f(vB[vaddr]);
            float dx = (2.0f/DD)*lr_sh[token]*(a2[nt][reg]-vv);
            uint16_t dv = f2bf(dx);
            dxA[d2*64 + (((token>>3) ^ (d2&7))<<3) + (token&7)] = dv;
            dxB[vaddr] = dv;               // vB slot, same addr as read
        }
    __syncthreads();

    // ---- G3: g2^T = dx2^T @ h. A = dxA swz, B = hA padded ----
    f32x4 a3[4];
    #pragma unroll
    for (int i=0;i<4;i++) a3[i]=(f32x4){0.f,0.f,0.f,0.f};
    gemm64u<1,0>(dxA, hA, w, q, col, a3);
    // ---- G4 (swapped): dh^T = w2 @ dx2^T. A = w2 GLOBAL, B = dxB swz ----
    f32x4 a4[4];
    #pragma unroll
    for (int i=0;i<4;i++) a4[i]=(f32x4){0.f,0.f,0.f,0.f};
    gemm64u<2,1>(w2b_bf, dxB, w, q, col, a4);

    size_t gb = (size_t)bhn*4096;
    #pragma unroll
    for (int nt=0;nt<4;nt++)
        #pragma unroll
        for (int reg=0;reg<4;reg++){
            int d2 = w*16 + q*4 + reg;
            int d1 = nt*16 + col;
            g2T[gb + d2*DD + d1] = f2bf(-a3[nt][reg]);
        }
    #pragma unroll
    for (int nt=0;nt<4;nt++)
        #pragma unroll
        for (int reg=0;reg<4;reg++){
            int idx = nt*4+reg;
            int d1 = w*16 + q*4 + reg;
            int token = nt*16 + col;
            float dsl = sg[idx] + hr[idx]*(1.f-sg[idx]);
            dx1T[d1*LDSP + token] = f2bf(a4[nt][reg]*dsl);   // hB slot (dead)
        }
    __syncthreads();

    // ---- G5: g1^T = dx1^T @ kc. A = dx1T padded, B = kcT swz ----
    f32x4 a5[4];
    #pragma unroll
    for (int i=0;i<4;i++) a5[i]=(f32x4){0.f,0.f,0.f,0.f};
    gemm64u<0,1>(dx1T, kcT, w, q, col, a5);
    #pragma unroll
    for (int nt=0;nt<4;nt++)
        #pragma unroll
        for (int reg=0;reg<4;reg++){
            int d1 = w*16 + q*4 + reg;
            int p  = nt*16 + col;
            g1T[gb + d1*DD + p] = f2bf(-a5[nt][reg]);
        }
}

// ---------------------------------------------------------------------------
// K5: merged scans (blk<256) + zero pads (blk 256..1272).
// zero's kb rows (8129+) are disjoint from gemm<1>'s writes (<=8128).
// ---------------------------------------------------------------------------
__global__ __launch_bounds__(256) void k_scan_zero(
    uint16_t* __restrict__ g1, uint16_t* __restrict__ g2,
    const float* __restrict__ mom, const float* __restrict__ dec,
    uint16_t* __restrict__ qbuf, float* __restrict__ out,
    float* __restrict__ gate_t)
{
    int blk = blockIdx.x;
    if (blk < 256){
        int arr = blk>>7; int rem = blk&127;
        int bh = rem>>2; int eg = rem&3;
        int e4 = eg*1024 + threadIdx.x*4;
        uint16_t* gp = arr ? g2 : g1;
        __shared__ float smg[NN], sdc[NN];
        if (threadIdx.x < NN){
            smg[threadIdx.x] = mom[bh*NN+threadIdx.x];
            sdc[threadIdx.x] = 1.f - dec[bh*NN+threadIdx.x];
        }
        __syncthreads();
        size_t base = (size_t)bh*NN*4096 + e4;
        float m0=0.f,m1=0.f,m2=0.f,m3=0.f, u0=0.f,u1=0.f,u2=0.f,u3=0.f;
        uint2 p0 = *(const uint2*)&gp[base];
        uint2 p1 = *(const uint2*)&gp[base + 4096];
        uint2 p2 = *(const uint2*)&gp[base + 2*4096];
        uint2 p3 = *(const uint2*)&gp[base + 3*4096];
        for (int t=0; t<NN; t+=4){
            uint2 c0=p0, c1=p1, c2=p2, c3=p3;
            if (t+4 < NN){                       // uniform branch
                p0 = *(const uint2*)&gp[base + (size_t)(t+4)*4096];
                p1 = *(const uint2*)&gp[base + (size_t)(t+5)*4096];
                p2 = *(const uint2*)&gp[base + (size_t)(t+6)*4096];
                p3 = *(const uint2*)&gp[base + (size_t)(t+7)*4096];
            }
            #pragma unroll
            for (int j=0;j<4;j++){
                uint2 c = (j==0)?c0:(j==1)?c1:(j==2)?c2:c3;
                float g = smg[t+j], d = sdc[t+j];
                float v0 = bf2f(c.x&0xffffu), v1 = bf2f(c.x>>16);
                float v2 = bf2f(c.y&0xffffu), v3 = bf2f(c.y>>16);
                m0 = fmaf(g,m0,v0); u0 = fmaf(d,u0,m0);
                m1 = fmaf(g,m1,v1); u1 = fmaf(d,u1,m1);
                m2 = fmaf(g,m2,v2); u2 = fmaf(d,u2,m2);
                m3 = fmaf(g,m3,v3); u3 = fmaf(d,u3,m3);
                uint2 r; r.x = pk2(u0,u1); r.y = pk2(u2,u3);
                *(uint2*)&gp[base + (size_t)(t+j)*4096] = r;
            }
        }
    } else {
        int g = (blk-256)*256 + threadIdx.x;
        const int QN = BHH*63*DD;          // 129024
        const int ON = BB*63*DIMM;         // 129024
        const int GN = BB*63*HH;           // 2016
        if (g < QN){
            int bh = g/4032; int r = g - bh*4032;
            int j = 8129 + (r>>6); int dk = r&63;
            qbuf[((size_t)bh*TT + j)*DD + dk] = 0;
        } else if (g < QN+ON){
            int g2i = g - QN;
            int b = g2i/(63*512); int r = g2i - b*63*512;
            int t = r>>9; int e = r&511;
            out[((size_t)b*TT + t)*DIMM + e] = 0.f;
        } else if (g < QN+ON+GN){
            int g3 = g - QN - ON;
            int b = g3/(63*HH); int r = g3 - b*63*HH;
            int j = 8129 + (r>>3); int hh = r&7;
            gate_t[((size_t)b*TT + j)*HH + hh] = 0.f;
        }
    }
}

// ---------------------------------------------------------------------------
// K6: retrieve via MFMA. One block per (bh,n), 4 waves.
// ---------------------------------------------------------------------------
__global__ __launch_bounds__(256) void k_retrieve(
    const uint16_t* __restrict__ qbuf, const uint16_t* __restrict__ u1T,
    const uint16_t* __restrict__ u2T, const float* __restrict__ w1Tf,
    const float* __restrict__ w2Tf, const float* __restrict__ gamma,
    const float* __restrict__ gate_t, uint16_t* __restrict__ y)
{
    __shared__ uint16_t qc[64*LDSP];
    __shared__ uint16_t W1s[64*LDSP];   // (w1+u1)^T rows: [d1][p]
    __shared__ uint16_t W2s[64*LDSP];   // (w2+u2)^T rows: [d2][d1]
    __shared__ uint16_t hB[64*LDSP];    // h rows: [token][d1]
    __shared__ float gate_sh[64], gam_sh[64];
    int bhn = blockIdx.x;
    int bh = bhn>>7, n = bhn&127;
    int b = bh>>3, h = bh&7;
    int tid = threadIdx.x, tx = tid&15, ty = tid>>4;
    int w = tid>>6, lane = tid&63, q = lane>>4, col = lane&15;
    size_t cbase = ((size_t)bh*TT + n*CC)*DD;
    size_t ub = (size_t)bhn*4096;

    #pragma unroll
    for (int r=0;r<4;r++){
        int row = ty*4+r;     // d_out index for W staging; token for qc
        *(ushort4*)&qc[row*LDSP + tx*4] =
            *(const ushort4*)&qbuf[cbase + row*DD + tx*4];
        ushort4 u14 = *(const ushort4*)&u1T[ub + row*DD + tx*4];
        float4 w1v = *(const float4*)&w1Tf[row*DD + tx*4];
        ushort4 s1;
        s1.x = f2bf(w1v.x + bf2f(u14.x));
        s1.y = f2bf(w1v.y + bf2f(u14.y));
        s1.z = f2bf(w1v.z + bf2f(u14.z));
        s1.w = f2bf(w1v.w + bf2f(u14.w));
        *(ushort4*)&W1s[row*LDSP + tx*4] = s1;
        ushort4 u24 = *(const ushort4*)&u2T[ub + row*DD + tx*4];
        float4 w2v = *(const float4*)&w2Tf[row*DD + tx*4];
        ushort4 s2;
        s2.x = f2bf(w2v.x + bf2f(u24.x));
        s2.y = f2bf(w2v.y + bf2f(u24.y));
        s2.z = f2bf(w2v.z + bf2f(u24.z));
        s2.w = f2bf(w2v.w + bf2f(u24.w));
        *(ushort4*)&W2s[row*LDSP + tx*4] = s2;
    }
    if (tid < 64){
        gate_sh[tid] = gate_t[((size_t)b*TT + n*CC + tid)*HH + h];
        gam_sh[tid]  = gamma[h*DD + tid];
    }
    __syncthreads();

    // G1: x1 = qc @ (w1+u1); h = silu
    f32x4 a1[4];
    #pragma unroll
    for (int i=0;i<4;i++) a1[i]=(f32x4){0.f,0.f,0.f,0.f};
    gemm64u<0,0>(qc, W1s, w, q, col, a1);
    #pragma unroll
    for (int nt=0;nt<4;nt++)
        #pragma unroll
        for (int reg=0;reg<4;reg++){
            float x = a1[nt][reg];
            int token = w*16 + q*4 + reg;
            int d1 = nt*16 + col;
            hB[token*LDSP + d1] = f2bf(x*sigmoidf_(x));
        }
    __syncthreads();

    // G2: x = h @ (w2+u2); rmsnorm(d=64) * (1+gamma) * gate -> y
    f32x4 a2[4];
    #pragma unroll
    for (int i=0;i<4;i++) a2[i]=(f32x4){0.f,0.f,0.f,0.f};
    gemm64u<0,0>(hB, W2s, w, q, col, a2);
    #pragma unroll
    for (int reg=0;reg<4;reg++){
        float p = 0.f;
        #pragma unroll
        for (int nt=0;nt<4;nt++) p += a2[nt][reg]*a2[nt][reg];
        p += __shfl_xor(p,1,64);
        p += __shfl_xor(p,2,64);
        p += __shfl_xor(p,4,64);
        p += __shfl_xor(p,8,64);
        float sclv = rsqrtf(p*(1.0f/DD)+EPS);
        int token = w*16 + q*4 + reg;
        float gt = gate_sh[token];
        size_t yb = ((size_t)b*TT + n*CC + token)*DIMM + h*DD;
        #pragma unroll
        for (int nt=0;nt<4;nt++){
            int d2 = nt*16 + col;
            y[yb + d2] = f2bf(a2[nt][reg]*sclv*(1.f+gam_sh[d2])*gt);
        }
    }
}

// ---------------------------------------------------------------------------
extern "C" void kernel_launch(void* const* d_in, const int* in_sizes, int n_in,
                              void* d_out, int out_size, void* d_ws, size_t ws_size,
                              hipStream_t stream)
{
    (void)in_sizes; (void)n_in; (void)out_size; (void)ws_size;
    const float* seq    = (const float*)d_in[0];
    const float* w1     = (const float*)d_in[1];
    const float* w2     = (const float*)d_in[2];
    const float* Wq     = (const float*)d_in[3];
    const float* Wkv    = (const float*)d_in[4];
    const float* Wstep  = (const float*)d_in[5];
    const float* Wmom   = (const float*)d_in[6];
    const float* Wdecay = (const float*)d_in[7];
    const float* Wgate  = (const float*)d_in[8];
    const float* Wcomb  = (const float*)d_in[9];
    const float* gamma  = (const float*)d_in[10];
    float* out = (float*)d_out;

    float* scale = (float*)d_ws;          // 32768
    float* lr_t  = scale + 32768;         // 262144  [b][t][h]
    float* gate_t= lr_t + 262144;         // 262144  [b][j][h]
    float* mom   = gate_t + 262144;       // 4096
    float* dec   = mom + 4096;            // 4096
    float* w1t_f = dec + 4096;            // 4096 f32 w1^T
    float* w2t_f = w1t_f + 4096;          // 4096 f32 w2^T
    uint16_t* w1t_bf = (uint16_t*)(w2t_f + 4096);  // [64][64] bf16 w1^T
    uint16_t* w2t_bf = w1t_bf + 4096;              // [64][64] bf16 w2^T
    uint16_t* w2b_bf = w2t_bf + 4096;              // [64][64] bf16 w2
    uint16_t* btkv = w2b_bf + 4096;          // 1024*512 bf16 [n][k]
    uint16_t* btq  = btkv + 1024*512;        // 512*512
    uint16_t* btc  = btq  + 512*512;         // 512*512
    uint16_t* kb = btc + 512*512;            // 16777216 bf16 (q reuses after k_grad)
    uint16_t* vb = kb + 16777216;            // 16777216 bf16 (y reuses after k_retrieve)
    uint16_t* g1 = vb + 16777216;            // 16777216 bf16 g1^T (scan -> upd1^T)
    uint16_t* g2 = g1 + 16777216;            // 16777216 bf16 g2^T (scan -> upd2^T)
    uint16_t* sbf = g1;                      // [32768][512] bf16 seq*scale —
                                             // aliases g1 (dead until k_grad)
    uint16_t* wsg = g2;                      // [16][512] bf16 [Wstep|Wgate]^T —
                                             // aliases g2 (dead until k_grad)

    k_prep <<<1057, 256, 0, stream>>>(Wkv, Wq, Wcomb, Wstep, Wgate, w1, w2,
                                      btkv, btq, btc, wsg,
                                      w1t_bf, w2t_bf, w2b_bf, w1t_f, w2t_f);
    k_scale    <<<8192, 256, 0, stream>>>(seq, scale, sbf);
    k_post_sbf <<<768, 256, 0, stream>>>(sbf, wsg, Wmom, Wdecay,
                                         lr_t, gate_t, mom, dec);
    k_gemm_mfma<0><<<dim3(8, 256), 256, 0, stream>>>(sbf, btkv, nullptr, kb, vb);
    k_grad   <<<BHH*NN, 256, 0, stream>>>(kb, vb, lr_t, w1t_bf, w2t_bf, w2b_bf, g1, g2);
    k_scan_zero<<<1273, 256, 0, stream>>>(g1, g2, mom, dec, kb /*q*/, out, gate_t);
    k_gemm_mfma<1><<<dim3(4, 256), 256, 0, stream>>>(seq, btq, scale, kb /*q*/, nullptr);
    k_retrieve<<<BHH*NN, 256, 0, stream>>>(kb /*q*/, g1, g2, w1t_f, w2t_f, gamma, gate_t, vb /*y*/);
    k_gemm_mfma<2><<<dim3(4, 256), 256, 0, stream>>>(vb /*y*/, btc, nullptr, out, nullptr);
}